// Round 3
// baseline (13413.214 us; speedup 1.0000x reference)
//
#include <hip/hip_runtime.h>

#define Bc 32
#define Kc 64
#define Wc 100
#define Hc 150
#define H3c 450
#define KWc 6400
#define ALPHAc 0.2f
#define THRESc 0.0002f

// ---- ws layout (float offsets), total 1,138,048 floats = 4.55 MB ----
#define OFF_WX      0u          // 204800  Wx (B,K,W) fp32
#define OFF_CS      204800u     // 2048    causesum (B,K)
#define OFF_GX      206848u     // 921600  gl proj (s,b,g)
#define OFF_HT      1128448u    // 4800    h_t (B,H)
#define OFF_Z       1133248u    // 4800    z (B,H)

// ---------- Wx = x @ lin_w.T + lin_b ----------
__global__ void wx_kernel(const float* __restrict__ x, const float* __restrict__ lin_w,
                          const float* __restrict__ lin_b, float* __restrict__ ws){
  int o = blockIdx.x*256 + threadIdx.x;
  if (o >= Bc*KWc) return;
  int i = o % Wc;
  int bk = o / Wc;
  const float4* xr = (const float4*)(x + bk*Wc);      // 400*bk bytes, 16-aligned
  const float4* wr = (const float4*)(lin_w + i*Wc);   // 400*i bytes, 16-aligned
  float acc = lin_b[i];
  #pragma unroll
  for (int j=0;j<25;j++){
    float4 xv = xr[j], wv = wr[j];
    acc += xv.x*wv.x + xv.y*wv.y + xv.z*wv.z + xv.w*wv.w;
  }
  ws[OFF_WX + o] = acc;
}

// ---------- attention: per (b,k) row, softmax over 6400, thresholded sum of v ----------
__global__ void attn_kernel(const float* __restrict__ y, const float* __restrict__ a,
                            const float* __restrict__ bias, float* __restrict__ ws){
  __shared__ float e_l[KWc];
  __shared__ float red[4];
  int row = blockIdx.x;          // b*64 + k
  int b = row >> 6, k = row & 63;
  int tid = threadIdx.x;
  float a0 = a[0], a1 = a[1];
  float yv = y[row];
  const float* v = ws + OFF_WX + b*KWc;
  const float* br = bias + k*KWc;
  float m = -3.4e38f;
  for (int j=tid; j<KWc; j+=256){
    float e = a0*yv + a1*v[j] + br[j];
    e = (e >= 0.f) ? e : ALPHAc*e;
    e_l[j] = e;
    m = fmaxf(m, e);
  }
  for (int o=32;o;o>>=1) m = fmaxf(m, __shfl_down(m, o));
  if ((tid&63)==0) red[tid>>6] = m;
  __syncthreads();
  m = fmaxf(fmaxf(red[0],red[1]), fmaxf(red[2],red[3]));
  __syncthreads();
  float ssum = 0.f;
  for (int j=tid; j<KWc; j+=256){
    float ex = expf(e_l[j]-m);
    e_l[j] = ex;                 // stash exp for pass 3
    ssum += ex;
  }
  for (int o=32;o;o>>=1) ssum += __shfl_down(ssum, o);
  if ((tid&63)==0) red[tid>>6] = ssum;
  __syncthreads();
  float s = red[0]+red[1]+red[2]+red[3];
  __syncthreads();
  float cs = 0.f;
  for (int j=tid; j<KWc; j+=256){
    float att = e_l[j] / s;
    if (att >= THRESc) cs += v[j];
  }
  for (int o=32;o;o>>=1) cs += __shfl_down(cs, o);
  if ((tid&63)==0) red[tid>>6] = cs;
  __syncthreads();
  if (tid==0) ws[OFF_CS + row] = red[0]+red[1]+red[2]+red[3];
}

// ---------- gl input projection: gx[s,b,g] = (Wx[b,s,:]+cs[b,s]) . gl_wih[g,:] + bih[g] ----------
__global__ void glproj_kernel(const float* __restrict__ gl_wih, const float* __restrict__ gl_bih,
                              float* __restrict__ ws){
  int o = blockIdx.x*256 + threadIdx.x;
  if (o >= Kc*Bc*H3c) return;
  int g = o % H3c;
  int t = o / H3c;               // s*32 + b
  int b = t & 31, s = t >> 5;
  float cs = ws[OFF_CS + b*Kc + s];
  const float4* xr = (const float4*)(ws + OFF_WX + b*KWc + s*Wc);  // 16-aligned
  const float4* wr = (const float4*)(gl_wih + g*Wc);               // 400g B, 16-aligned
  float acc = gl_bih[g];
  #pragma unroll
  for (int j=0;j<25;j++){
    float4 wv = wr[j], xv = xr[j];
    acc += (xv.x+cs)*wv.x + (xv.y+cs)*wv.y + (xv.z+cs)*wv.z + (xv.w+cs)*wv.w;
  }
  ws[OFF_GX + o] = acc;
}

// ---------- gl recurrent GRU: one block per batch b, raw f32 gl_whh ----------
__global__ void glgru_kernel(const float* __restrict__ gl_whh, const float* __restrict__ gl_bhh,
                             float* __restrict__ ws){
  __shared__ __align__(16) float h_l[152];
  __shared__ float gh_l[H3c];
  int b = blockIdx.x, tid = threadIdx.x;
  if (tid < 152) h_l[tid] = 0.f;
  for (int s=0;s<Kc;s++){
    __syncthreads();
    if (tid < H3c){
      const float2* wr = (const float2*)(gl_whh + tid*Hc);   // 600*tid B, 8-aligned
      const float2* hr = (const float2*)h_l;
      float acc = gl_bhh[tid];
      #pragma unroll
      for (int j=0;j<75;j++){
        float2 wv = wr[j], hv = hr[j];
        acc += wv.x*hv.x + wv.y*hv.y;
      }
      gh_l[tid] = acc;
    }
    __syncthreads();
    if (tid < Hc){
      const float* gx = ws + OFF_GX + (s*Bc + b)*H3c;
      float r  = 1.f/(1.f+expf(-(gx[tid]      + gh_l[tid])));
      float zz = 1.f/(1.f+expf(-(gx[Hc+tid]   + gh_l[Hc+tid])));
      float n  = tanhf(gx[2*Hc+tid] + r*gh_l[2*Hc+tid]);
      h_l[tid] = (1.f-zz)*n + zz*h_l[tid];
    }
  }
  __syncthreads();
  if (tid < Hc) ws[OFF_HT + b*Hc + tid] = h_l[tid];
}

// ---------- z = mu + sigma * z_noise ----------
__global__ void z_kernel(const float* __restrict__ z_noise, const float* __restrict__ mu_w,
                         const float* __restrict__ mu_b, const float* __restrict__ std_w,
                         const float* __restrict__ std_b, float* __restrict__ ws){
  int o = blockIdx.x*256 + threadIdx.x;
  if (o >= Bc*Hc) return;
  int t = o % Hc, b = o / Hc;
  const float* h = ws + OFF_HT + b*Hc;
  const float2* mwr = (const float2*)(mu_w + t*Hc);   // 600t bytes, 8-aligned
  const float2* swr = (const float2*)(std_w + t*Hc);
  float mu = mu_b[t], lv = std_b[t];
  for (int j=0;j<Hc/2;j++){
    float2 mw = mwr[j], sw = swr[j];
    float h0 = h[2*j], h1 = h[2*j+1];
    mu += h0*mw.x + h1*mw.y;
    lv += h0*sw.x + h1*sw.y;
  }
  float sg = expf(0.5f*lv);
  ws[OFF_Z + o] = mu + sg*z_noise[o];
}

// ---------- causes: 64 nets x 32 chains, block = (net k, 8-batch group), raw f32 weights ----------
__global__ void causes_kernel(const float* __restrict__ net_wih, const float* __restrict__ net_whh,
                              const float* __restrict__ net_bih, const float* __restrict__ net_bhh,
                              const float* __restrict__ ws, float* __restrict__ out){
  __shared__ __align__(16) float h_l[8*152];
  __shared__ __align__(16) float xs_l[8*104];
  __shared__ float gh_l[H3c*8];
  __shared__ float gp_l[H3c*8];
  int kk = blockIdx.x >> 2, bg = blockIdx.x & 3, b0 = bg*8;
  int tid = threadIdx.x;
  for (int it=tid; it<1200; it+=512){
    int bb = it & 7, t = it >> 3;
    h_l[bb*152+t] = ws[OFF_Z + (b0+bb)*Hc + t];
  }
  if (tid < 8){
    h_l[tid*152+150]=0.f; h_l[tid*152+151]=0.f;
    xs_l[tid*104+100]=0.f; xs_l[tid*104+101]=0.f;
    xs_l[tid*104+102]=0.f; xs_l[tid*104+103]=0.f;
  }
  const float* wihb = net_wih + (size_t)kk*H3c*Wc;
  const float* whhb = net_whh + (size_t)kk*H3c*Hc;
  const float* bih = net_bih + kk*H3c;
  const float* bhh = net_bhh + kk*H3c;
  for (int s=0;s<Kc;s++){
    __syncthreads();
    for (int it=tid; it<800; it+=512){
      int bb = it/100, i = it%100;
      xs_l[bb*104+i] = ws[OFF_WX + (b0+bb)*KWc + s*Wc + i];
    }
    __syncthreads();
    for (int it=tid; it<3600; it+=512){
      int g = it >> 3, bb = it & 7;
      float acc1 = bhh[g];
      const float2* wr = (const float2*)(whhb + (size_t)g*Hc);   // 600g B, 8-aligned
      const float2* hr = (const float2*)(h_l + bb*152);          // 608bb B, 8-aligned
      #pragma unroll
      for (int j=0;j<75;j++){
        float2 wv = wr[j], hv = hr[j];
        acc1 += wv.x*hv.x + wv.y*hv.y;
      }
      float acc2 = bih[g];
      const float4* wr2 = (const float4*)(wihb + (size_t)g*Wc);  // 400g B, 16-aligned
      const float4* xr = (const float4*)(xs_l + bb*104);         // 416bb B, 16-aligned
      #pragma unroll
      for (int j=0;j<25;j++){
        float4 wv = wr2[j], xv = xr[j];
        acc2 += wv.x*xv.x + wv.y*xv.y + wv.z*xv.z + wv.w*xv.w;
      }
      gh_l[g*8+bb] = acc1;
      gp_l[g*8+bb] = acc2;
    }
    __syncthreads();
    for (int it=tid; it<1200; it+=512){
      int t = it >> 3, bb = it & 7;
      float r  = 1.f/(1.f+expf(-(gp_l[t*8+bb] + gh_l[t*8+bb])));
      float zz = 1.f/(1.f+expf(-(gp_l[(Hc+t)*8+bb] + gh_l[(Hc+t)*8+bb])));
      float n  = tanhf(gp_l[(2*Hc+t)*8+bb] + r*gh_l[(2*Hc+t)*8+bb]);
      h_l[bb*152+t] = (1.f-zz)*n + zz*h_l[bb*152+t];
    }
  }
  __syncthreads();
  for (int it=tid; it<1200; it+=512){
    int t = it >> 3, bb = it & 7;
    out[((b0+bb)*Kc + kk)*Hc + t] = h_l[bb*152+t];
  }
}

extern "C" void kernel_launch(void* const* d_in, const int* in_sizes, int n_in,
                              void* d_out, int out_size, void* d_ws, size_t ws_size,
                              hipStream_t stream){
  const float* x        = (const float*)d_in[0];
  const float* y        = (const float*)d_in[1];
  const float* z_noise  = (const float*)d_in[2];
  const float* lin_w    = (const float*)d_in[3];
  const float* lin_b    = (const float*)d_in[4];
  const float* a        = (const float*)d_in[5];
  const float* bias     = (const float*)d_in[6];
  const float* gl_wih   = (const float*)d_in[7];
  const float* gl_whh   = (const float*)d_in[8];
  const float* gl_bih   = (const float*)d_in[9];
  const float* gl_bhh   = (const float*)d_in[10];
  const float* mu_w     = (const float*)d_in[11];
  const float* mu_b     = (const float*)d_in[12];
  const float* std_w    = (const float*)d_in[13];
  const float* std_b    = (const float*)d_in[14];
  const float* net_wih  = (const float*)d_in[15];
  const float* net_whh  = (const float*)d_in[16];
  const float* net_bih  = (const float*)d_in[17];
  const float* net_bhh  = (const float*)d_in[18];
  float* ws = (float*)d_ws;
  float* out = (float*)d_out;

  wx_kernel<<<(Bc*KWc+255)/256, 256, 0, stream>>>(x, lin_w, lin_b, ws);
  attn_kernel<<<Bc*Kc, 256, 0, stream>>>(y, a, bias, ws);
  glproj_kernel<<<(Kc*Bc*H3c+255)/256, 256, 0, stream>>>(gl_wih, gl_bih, ws);
  glgru_kernel<<<Bc, 512, 0, stream>>>(gl_whh, gl_bhh, ws);
  z_kernel<<<(Bc*Hc+255)/256, 256, 0, stream>>>(z_noise, mu_w, mu_b, std_w, std_b, ws);
  causes_kernel<<<Kc*4, 512, 0, stream>>>(net_wih, net_whh, net_bih, net_bhh, ws, out);
}

// Round 4
// 1822.631 us; speedup vs baseline: 7.3593x; 7.3593x over previous
//
#include <hip/hip_runtime.h>

#define Bc 32
#define Kc 64
#define Wc 100
#define Hc 150
#define H3c 450
#define KWc 6400
#define ALPHAc 0.2f
#define THRESc 0.0002f

typedef unsigned int u32;
typedef unsigned short u16;

// ---- ws layout ----
// f32 region (float offsets):
#define OFF_WX      0u          // 204800  Wx (B,K,W) fp32
#define OFF_CS      204800u     // 2048    causesum (B,K)
#define OFF_GX      206848u     // 921600  gl proj (s,b,g)
#define OFF_HT      1128448u    // 4800    h_t (B,H)
#define OFF_Z       1133248u    // 4800    z (B,H)
#define OFF_F32_END 1138048u    // floats
// u16 region (u16 offsets from (u16*)ws):
#define OFF16_WIH   2276096u    // 2,880,000 u16: net_wih bf16 (64,450,100)
#define OFF16_WHH   5156096u    // 4,320,000 u16: net_whh bf16 (64,450,150)
#define WS_NEED_BYTES 18952192u

__device__ __forceinline__ float lo2f(u32 w){ return __uint_as_float(w<<16); }
__device__ __forceinline__ float hi2f(u32 w){ return __uint_as_float(w & 0xffff0000u); }
__device__ __forceinline__ u16 f2us(float f){
  u32 x = __float_as_uint(f);
  u32 r = (x + 0x7fffu + ((x>>16)&1u)) >> 16;   // RNE bf16
  return (u16)r;
}

// ---------- prologue: net weights -> bf16 in ws ----------
__global__ void conv16_kernel(const float* __restrict__ wih, const float* __restrict__ whh,
                              u16* __restrict__ w16){
  const int N1 = Kc*H3c*Wc;          // 2,880,000
  const int NT = N1 + Kc*H3c*Hc;     // 7,200,000
  for (int i = blockIdx.x*256 + threadIdx.x; i < NT; i += gridDim.x*256){
    float v = (i < N1) ? wih[i] : whh[i - N1];
    w16[OFF16_WIH + i] = f2us(v);    // WHH16 region starts exactly at OFF16_WIH+N1
  }
}

// ---------- Wx = x @ lin_w.T + lin_b ----------
__global__ void wx_kernel(const float* __restrict__ x, const float* __restrict__ lin_w,
                          const float* __restrict__ lin_b, float* __restrict__ ws){
  int o = blockIdx.x*256 + threadIdx.x;
  if (o >= Bc*KWc) return;
  int i = o % Wc;
  int bk = o / Wc;
  const float4* xr = (const float4*)(x + bk*Wc);
  const float4* wr = (const float4*)(lin_w + i*Wc);
  float acc = lin_b[i];
  #pragma unroll
  for (int j=0;j<25;j++){
    float4 xv = xr[j], wv = wr[j];
    acc += xv.x*wv.x + xv.y*wv.y + xv.z*wv.z + xv.w*wv.w;
  }
  ws[OFF_WX + o] = acc;
}

// ---------- attention softmax + thresholded sum ----------
__global__ void attn_kernel(const float* __restrict__ y, const float* __restrict__ a,
                            const float* __restrict__ bias, float* __restrict__ ws){
  __shared__ float e_l[KWc];
  __shared__ float red[4];
  int row = blockIdx.x;          // b*64 + k
  int b = row >> 6, k = row & 63;
  int tid = threadIdx.x;
  float a0 = a[0], a1 = a[1];
  float yv = y[row];
  const float* v = ws + OFF_WX + b*KWc;
  const float* br = bias + k*KWc;
  float m = -3.4e38f;
  for (int j=tid; j<KWc; j+=256){
    float e = a0*yv + a1*v[j] + br[j];
    e = (e >= 0.f) ? e : ALPHAc*e;
    e_l[j] = e;
    m = fmaxf(m, e);
  }
  for (int o=32;o;o>>=1) m = fmaxf(m, __shfl_down(m, o));
  if ((tid&63)==0) red[tid>>6] = m;
  __syncthreads();
  m = fmaxf(fmaxf(red[0],red[1]), fmaxf(red[2],red[3]));
  __syncthreads();
  float ssum = 0.f;
  for (int j=tid; j<KWc; j+=256){
    float ex = expf(e_l[j]-m);
    e_l[j] = ex;
    ssum += ex;
  }
  for (int o=32;o;o>>=1) ssum += __shfl_down(ssum, o);
  if ((tid&63)==0) red[tid>>6] = ssum;
  __syncthreads();
  float s = red[0]+red[1]+red[2]+red[3];
  __syncthreads();
  float cs = 0.f;
  for (int j=tid; j<KWc; j+=256){
    float att = e_l[j] / s;
    if (att >= THRESc) cs += v[j];
  }
  for (int o=32;o;o>>=1) cs += __shfl_down(cs, o);
  if ((tid&63)==0) red[tid>>6] = cs;
  __syncthreads();
  if (tid==0) ws[OFF_CS + row] = red[0]+red[1]+red[2]+red[3];
}

// ---------- gl input projection ----------
__global__ void glproj_kernel(const float* __restrict__ gl_wih, const float* __restrict__ gl_bih,
                              float* __restrict__ ws){
  int o = blockIdx.x*256 + threadIdx.x;
  if (o >= Kc*Bc*H3c) return;
  int g = o % H3c;
  int t = o / H3c;               // s*32 + b
  int b = t & 31, s = t >> 5;
  float cs = ws[OFF_CS + b*Kc + s];
  const float4* xr = (const float4*)(ws + OFF_WX + b*KWc + s*Wc);
  const float4* wr = (const float4*)(gl_wih + g*Wc);
  float acc = gl_bih[g];
  #pragma unroll
  for (int j=0;j<25;j++){
    float4 wv = wr[j], xv = xr[j];
    acc += (xv.x+cs)*wv.x + (xv.y+cs)*wv.y + (xv.z+cs)*wv.z + (xv.w+cs)*wv.w;
  }
  ws[OFF_GX + o] = acc;
}

// ---------- gl recurrent GRU ----------
__global__ void glgru_kernel(const float* __restrict__ gl_whh, const float* __restrict__ gl_bhh,
                             float* __restrict__ ws){
  __shared__ __align__(16) float h_l[152];
  __shared__ float gh_l[H3c];
  int b = blockIdx.x, tid = threadIdx.x;
  if (tid < 152) h_l[tid] = 0.f;
  for (int s=0;s<Kc;s++){
    __syncthreads();
    if (tid < H3c){
      const float2* wr = (const float2*)(gl_whh + tid*Hc);
      const float2* hr = (const float2*)h_l;
      float acc = gl_bhh[tid];
      #pragma unroll
      for (int j=0;j<75;j++){
        float2 wv = wr[j], hv = hr[j];
        acc += wv.x*hv.x + wv.y*hv.y;
      }
      gh_l[tid] = acc;
    }
    __syncthreads();
    if (tid < Hc){
      const float* gx = ws + OFF_GX + (s*Bc + b)*H3c;
      float r  = 1.f/(1.f+expf(-(gx[tid]      + gh_l[tid])));
      float zz = 1.f/(1.f+expf(-(gx[Hc+tid]   + gh_l[Hc+tid])));
      float n  = tanhf(gx[2*Hc+tid] + r*gh_l[2*Hc+tid]);
      h_l[tid] = (1.f-zz)*n + zz*h_l[tid];
    }
  }
  __syncthreads();
  if (tid < Hc) ws[OFF_HT + b*Hc + tid] = h_l[tid];
}

// ---------- z = mu + sigma * z_noise ----------
__global__ void z_kernel(const float* __restrict__ z_noise, const float* __restrict__ mu_w,
                         const float* __restrict__ mu_b, const float* __restrict__ std_w,
                         const float* __restrict__ std_b, float* __restrict__ ws){
  int o = blockIdx.x*256 + threadIdx.x;
  if (o >= Bc*Hc) return;
  int t = o % Hc, b = o / Hc;
  const float* h = ws + OFF_HT + b*Hc;
  const float2* mwr = (const float2*)(mu_w + t*Hc);
  const float2* swr = (const float2*)(std_w + t*Hc);
  float mu = mu_b[t], lv = std_b[t];
  for (int j=0;j<Hc/2;j++){
    float2 mw = mwr[j], sw = swr[j];
    float h0 = h[2*j], h1 = h[2*j+1];
    mu += h0*mw.x + h1*mw.y;
    lv += h0*sw.x + h1*sw.y;
  }
  float sg = expf(0.5f*lv);
  ws[OFF_Z + o] = mu + sg*z_noise[o];
}

// ---------- causes v2: bf16 weights from L2 (XCD-affinity), per-thread 3-gate tasks ----------
// block = bg*64+kk : same net's 4 blocks land on the same XCD (%8 round-robin)
__global__ void __launch_bounds__(512) causes2_kernel(
    const u16* __restrict__ w16,
    const float* __restrict__ net_bih, const float* __restrict__ net_bhh,
    const float* __restrict__ ws, float* __restrict__ out){
  __shared__ __align__(8) float xs_l[8*100];
  __shared__ __align__(8) float h_l[8*152];
  int kk = blockIdx.x & 63, bg = blockIdx.x >> 6, b0 = bg*8;
  int tid = threadIdx.x;
  for (int it=tid; it<1200; it+=512){
    int t = it>>3, bb = it&7;
    h_l[bb*152+t] = ws[OFF_Z + (b0+bb)*Hc + t];
  }
  if (tid < 8){ h_l[tid*152+150]=0.f; h_l[tid*152+151]=0.f; }
  const u32* wihk = (const u32*)(w16 + OFF16_WIH) + (size_t)kk*22500u;  // 450 rows x 50 u32
  const u32* whhk = (const u32*)(w16 + OFF16_WHH) + (size_t)kk*33750u;  // 450 rows x 75 u32
  const float* bih = net_bih + kk*H3c;
  const float* bhh = net_bhh + kk*H3c;
  int t0[3]; int nt=0;
  for (int task=tid; task<1200; task+=512) t0[nt++] = task;
  float hnew[3];
  for (int s=0;s<Kc;s++){
    __syncthreads();
    for (int it=tid; it<800; it+=512){
      int bb = it/100, i = it%100;
      xs_l[bb*100+i] = ws[OFF_WX + (b0+bb)*KWc + s*Wc + i];
    }
    __syncthreads();
    for (int q=0;q<nt;q++){
      int task = t0[q]; int t = task>>3, bb = task&7;
      const u32* wr_r = whhk + t*75;
      const u32* wr_z = whhk + (150+t)*75;
      const u32* wr_n = whhk + (300+t)*75;
      const float2* hp = (const float2*)(h_l + bb*152);
      float a_r  = bhh[t]      + bih[t];
      float a_z  = bhh[150+t]  + bih[150+t];
      float a_nh = bhh[300+t];
      float a_np = bih[300+t];
      #pragma unroll 15
      for (int j=0;j<75;j++){
        float2 hv = hp[j];
        u32 w1 = wr_r[j], w2 = wr_z[j], w3 = wr_n[j];
        a_r  += lo2f(w1)*hv.x + hi2f(w1)*hv.y;
        a_z  += lo2f(w2)*hv.x + hi2f(w2)*hv.y;
        a_nh += lo2f(w3)*hv.x + hi2f(w3)*hv.y;
      }
      const u32* vr_r = wihk + t*50;
      const u32* vr_z = wihk + (150+t)*50;
      const u32* vr_n = wihk + (300+t)*50;
      const float2* xp = (const float2*)(xs_l + bb*100);
      #pragma unroll 10
      for (int j=0;j<50;j++){
        float2 xv = xp[j];
        u32 w1 = vr_r[j], w2 = vr_z[j], w3 = vr_n[j];
        a_r  += lo2f(w1)*xv.x + hi2f(w1)*xv.y;
        a_z  += lo2f(w2)*xv.x + hi2f(w2)*xv.y;
        a_np += lo2f(w3)*xv.x + hi2f(w3)*xv.y;
      }
      float r  = 1.f/(1.f+__expf(-a_r));
      float zz = 1.f/(1.f+__expf(-a_z));
      float nx = a_np + r*a_nh;
      nx = fminf(fmaxf(nx, -15.f), 15.f);
      float e2 = __expf(2.f*nx);
      float n = (e2-1.f)/(e2+1.f);
      hnew[q] = (1.f-zz)*n + zz*h_l[bb*152+t];
    }
    __syncthreads();
    for (int q=0;q<nt;q++){
      int task = t0[q];
      h_l[(task&7)*152 + (task>>3)] = hnew[q];
    }
  }
  __syncthreads();
  for (int q=0;q<nt;q++){
    int task = t0[q]; int t = task>>3, bb = task&7;
    out[((b0+bb)*Kc + kk)*Hc + t] = h_l[bb*152+t];
  }
}

// ---------- fallback (round-3 path, f32 streaming) if ws too small ----------
__global__ void causes_f32_kernel(const float* __restrict__ net_wih, const float* __restrict__ net_whh,
                                  const float* __restrict__ net_bih, const float* __restrict__ net_bhh,
                                  const float* __restrict__ ws, float* __restrict__ out){
  __shared__ __align__(16) float h_l[8*152];
  __shared__ __align__(16) float xs_l[8*104];
  __shared__ float gh_l[H3c*8];
  __shared__ float gp_l[H3c*8];
  int kk = blockIdx.x >> 2, bg = blockIdx.x & 3, b0 = bg*8;
  int tid = threadIdx.x;
  for (int it=tid; it<1200; it+=512){
    int bb = it & 7, t = it >> 3;
    h_l[bb*152+t] = ws[OFF_Z + (b0+bb)*Hc + t];
  }
  if (tid < 8){
    h_l[tid*152+150]=0.f; h_l[tid*152+151]=0.f;
    xs_l[tid*104+100]=0.f; xs_l[tid*104+101]=0.f;
    xs_l[tid*104+102]=0.f; xs_l[tid*104+103]=0.f;
  }
  const float* wihb = net_wih + (size_t)kk*H3c*Wc;
  const float* whhb = net_whh + (size_t)kk*H3c*Hc;
  const float* bih = net_bih + kk*H3c;
  const float* bhh = net_bhh + kk*H3c;
  for (int s=0;s<Kc;s++){
    __syncthreads();
    for (int it=tid; it<800; it+=512){
      int bb = it/100, i = it%100;
      xs_l[bb*104+i] = ws[OFF_WX + (b0+bb)*KWc + s*Wc + i];
    }
    __syncthreads();
    for (int it=tid; it<3600; it+=512){
      int g = it >> 3, bb = it & 7;
      float acc1 = bhh[g];
      const float2* wr = (const float2*)(whhb + (size_t)g*Hc);
      const float2* hr = (const float2*)(h_l + bb*152);
      #pragma unroll
      for (int j=0;j<75;j++){
        float2 wv = wr[j], hv = hr[j];
        acc1 += wv.x*hv.x + wv.y*hv.y;
      }
      float acc2 = bih[g];
      const float4* wr2 = (const float4*)(wihb + (size_t)g*Wc);
      const float4* xr = (const float4*)(xs_l + bb*104);
      #pragma unroll
      for (int j=0;j<25;j++){
        float4 wv = wr2[j], xv = xr[j];
        acc2 += wv.x*xv.x + wv.y*xv.y + wv.z*xv.z + wv.w*xv.w;
      }
      gh_l[g*8+bb] = acc1;
      gp_l[g*8+bb] = acc2;
    }
    __syncthreads();
    for (int it=tid; it<1200; it+=512){
      int t = it >> 3, bb = it & 7;
      float r  = 1.f/(1.f+expf(-(gp_l[t*8+bb] + gh_l[t*8+bb])));
      float zz = 1.f/(1.f+expf(-(gp_l[(Hc+t)*8+bb] + gh_l[(Hc+t)*8+bb])));
      float n  = tanhf(gp_l[(2*Hc+t)*8+bb] + r*gh_l[(2*Hc+t)*8+bb]);
      h_l[bb*152+t] = (1.f-zz)*n + zz*h_l[bb*152+t];
    }
  }
  __syncthreads();
  for (int it=tid; it<1200; it+=512){
    int t = it >> 3, bb = it & 7;
    out[((b0+bb)*Kc + kk)*Hc + t] = h_l[bb*152+t];
  }
}

extern "C" void kernel_launch(void* const* d_in, const int* in_sizes, int n_in,
                              void* d_out, int out_size, void* d_ws, size_t ws_size,
                              hipStream_t stream){
  const float* x        = (const float*)d_in[0];
  const float* y        = (const float*)d_in[1];
  const float* z_noise  = (const float*)d_in[2];
  const float* lin_w    = (const float*)d_in[3];
  const float* lin_b    = (const float*)d_in[4];
  const float* a        = (const float*)d_in[5];
  const float* bias     = (const float*)d_in[6];
  const float* gl_wih   = (const float*)d_in[7];
  const float* gl_whh   = (const float*)d_in[8];
  const float* gl_bih   = (const float*)d_in[9];
  const float* gl_bhh   = (const float*)d_in[10];
  const float* mu_w     = (const float*)d_in[11];
  const float* mu_b     = (const float*)d_in[12];
  const float* std_w    = (const float*)d_in[13];
  const float* std_b    = (const float*)d_in[14];
  const float* net_wih  = (const float*)d_in[15];
  const float* net_whh  = (const float*)d_in[16];
  const float* net_bih  = (const float*)d_in[17];
  const float* net_bhh  = (const float*)d_in[18];
  float* ws = (float*)d_ws;
  float* out = (float*)d_out;
  bool big = ws_size >= (size_t)WS_NEED_BYTES;

  if (big)
    conv16_kernel<<<2048, 256, 0, stream>>>(net_wih, net_whh, (u16*)d_ws);
  wx_kernel<<<(Bc*KWc+255)/256, 256, 0, stream>>>(x, lin_w, lin_b, ws);
  attn_kernel<<<Bc*Kc, 256, 0, stream>>>(y, a, bias, ws);
  glproj_kernel<<<(Kc*Bc*H3c+255)/256, 256, 0, stream>>>(gl_wih, gl_bih, ws);
  glgru_kernel<<<Bc, 512, 0, stream>>>(gl_whh, gl_bhh, ws);
  z_kernel<<<(Bc*Hc+255)/256, 256, 0, stream>>>(z_noise, mu_w, mu_b, std_w, std_b, ws);
  if (big)
    causes2_kernel<<<Kc*4, 512, 0, stream>>>((const u16*)d_ws, net_bih, net_bhh, ws, out);
  else
    causes_f32_kernel<<<Kc*4, 512, 0, stream>>>(net_wih, net_whh, net_bih, net_bhh, ws, out);
}

// Round 5
// 787.593 us; speedup vs baseline: 17.0306x; 2.3142x over previous
//
#include <hip/hip_runtime.h>

#define Bc 32
#define Kc 64
#define Wc 100
#define Hc 150
#define H3c 450
#define KWc 6400
#define ALPHAc 0.2f
#define THRESc 0.0002f

typedef unsigned int u32;
typedef unsigned short u16;
typedef __attribute__((ext_vector_type(8))) short short8;   // 8 bf16
typedef __attribute__((ext_vector_type(4))) float floatx4;  // 4 f32 acc

// ---- ws layout (float offsets), 4.55 MB ----
#define OFF_WX      0u          // 204800  Wx (B,K,W) fp32
#define OFF_CS      204800u     // 2048    causesum (B,K)
#define OFF_GX      206848u     // 921600  gl proj (s,b,g)
#define OFF_HT      1128448u    // 4800    h_t (B,H)
#define OFF_Z       1133248u    // 4800    z (B,H)

__device__ __forceinline__ float us2f(u16 u){ u32 x=((u32)u)<<16; return __uint_as_float(x); }
__device__ __forceinline__ u16 f2us(float f){
  u32 x = __float_as_uint(f);
  u32 r = (x + 0x7fffu + ((x>>16)&1u)) >> 16;   // RNE bf16
  return (u16)r;
}

// ---------- Wx = x @ lin_w.T + lin_b ----------
__global__ void wx_kernel(const float* __restrict__ x, const float* __restrict__ lin_w,
                          const float* __restrict__ lin_b, float* __restrict__ ws){
  int o = blockIdx.x*256 + threadIdx.x;
  if (o >= Bc*KWc) return;
  int i = o % Wc;
  int bk = o / Wc;
  const float4* xr = (const float4*)(x + bk*Wc);
  const float4* wr = (const float4*)(lin_w + i*Wc);
  float acc = lin_b[i];
  #pragma unroll
  for (int j=0;j<25;j++){
    float4 xv = xr[j], wv = wr[j];
    acc += xv.x*wv.x + xv.y*wv.y + xv.z*wv.z + xv.w*wv.w;
  }
  ws[OFF_WX + o] = acc;
}

// ---------- attention softmax + thresholded sum ----------
__global__ void attn_kernel(const float* __restrict__ y, const float* __restrict__ a,
                            const float* __restrict__ bias, float* __restrict__ ws){
  __shared__ float e_l[KWc];
  __shared__ float red[4];
  int row = blockIdx.x;          // b*64 + k
  int b = row >> 6, k = row & 63;
  int tid = threadIdx.x;
  float a0 = a[0], a1 = a[1];
  float yv = y[row];
  const float* v = ws + OFF_WX + b*KWc;
  const float* br = bias + k*KWc;
  float m = -3.4e38f;
  for (int j=tid; j<KWc; j+=256){
    float e = a0*yv + a1*v[j] + br[j];
    e = (e >= 0.f) ? e : ALPHAc*e;
    e_l[j] = e;
    m = fmaxf(m, e);
  }
  for (int o=32;o;o>>=1) m = fmaxf(m, __shfl_down(m, o));
  if ((tid&63)==0) red[tid>>6] = m;
  __syncthreads();
  m = fmaxf(fmaxf(red[0],red[1]), fmaxf(red[2],red[3]));
  __syncthreads();
  float ssum = 0.f;
  for (int j=tid; j<KWc; j+=256){
    float ex = expf(e_l[j]-m);
    e_l[j] = ex;
    ssum += ex;
  }
  for (int o=32;o;o>>=1) ssum += __shfl_down(ssum, o);
  if ((tid&63)==0) red[tid>>6] = ssum;
  __syncthreads();
  float s = red[0]+red[1]+red[2]+red[3];
  __syncthreads();
  float cs = 0.f;
  for (int j=tid; j<KWc; j+=256){
    float att = e_l[j] / s;
    if (att >= THRESc) cs += v[j];
  }
  for (int o=32;o;o>>=1) cs += __shfl_down(cs, o);
  if ((tid&63)==0) red[tid>>6] = cs;
  __syncthreads();
  if (tid==0) ws[OFF_CS + row] = red[0]+red[1]+red[2]+red[3];
}

// ---------- gl input projection ----------
__global__ void glproj_kernel(const float* __restrict__ gl_wih, const float* __restrict__ gl_bih,
                              float* __restrict__ ws){
  int o = blockIdx.x*256 + threadIdx.x;
  if (o >= Kc*Bc*H3c) return;
  int g = o % H3c;
  int t = o / H3c;               // s*32 + b
  int b = t & 31, s = t >> 5;
  float cs = ws[OFF_CS + b*Kc + s];
  const float4* xr = (const float4*)(ws + OFF_WX + b*KWc + s*Wc);
  const float4* wr = (const float4*)(gl_wih + g*Wc);
  float acc = gl_bih[g];
  #pragma unroll
  for (int j=0;j<25;j++){
    float4 wv = wr[j], xv = xr[j];
    acc += (xv.x+cs)*wv.x + (xv.y+cs)*wv.y + (xv.z+cs)*wv.z + (xv.w+cs)*wv.w;
  }
  ws[OFF_GX + o] = acc;
}

// ---------- gl recurrent GRU ----------
__global__ void glgru_kernel(const float* __restrict__ gl_whh, const float* __restrict__ gl_bhh,
                             float* __restrict__ ws){
  __shared__ __align__(16) float h_l[152];
  __shared__ float gh_l[H3c];
  int b = blockIdx.x, tid = threadIdx.x;
  if (tid < 152) h_l[tid] = 0.f;
  for (int s=0;s<Kc;s++){
    __syncthreads();
    if (tid < H3c){
      const float2* wr = (const float2*)(gl_whh + tid*Hc);
      const float2* hr = (const float2*)h_l;
      float acc = gl_bhh[tid];
      #pragma unroll
      for (int j=0;j<75;j++){
        float2 wv = wr[j], hv = hr[j];
        acc += wv.x*hv.x + wv.y*hv.y;
      }
      gh_l[tid] = acc;
    }
    __syncthreads();
    if (tid < Hc){
      const float* gx = ws + OFF_GX + (s*Bc + b)*H3c;
      float r  = 1.f/(1.f+expf(-(gx[tid]      + gh_l[tid])));
      float zz = 1.f/(1.f+expf(-(gx[Hc+tid]   + gh_l[Hc+tid])));
      float n  = tanhf(gx[2*Hc+tid] + r*gh_l[2*Hc+tid]);
      h_l[tid] = (1.f-zz)*n + zz*h_l[tid];
    }
  }
  __syncthreads();
  if (tid < Hc) ws[OFF_HT + b*Hc + tid] = h_l[tid];
}

// ---------- z = mu + sigma * z_noise ----------
__global__ void z_kernel(const float* __restrict__ z_noise, const float* __restrict__ mu_w,
                         const float* __restrict__ mu_b, const float* __restrict__ std_w,
                         const float* __restrict__ std_b, float* __restrict__ ws){
  int o = blockIdx.x*256 + threadIdx.x;
  if (o >= Bc*Hc) return;
  int t = o % Hc, b = o / Hc;
  const float* h = ws + OFF_HT + b*Hc;
  const float2* mwr = (const float2*)(mu_w + t*Hc);
  const float2* swr = (const float2*)(std_w + t*Hc);
  float mu = mu_b[t], lv = std_b[t];
  for (int j=0;j<Hc/2;j++){
    float2 mw = mwr[j], sw = swr[j];
    float h0 = h[2*j], h1 = h[2*j+1];
    mu += h0*mw.x + h1*mw.y;
    lv += h0*sw.x + h1*sw.y;
  }
  float sg = expf(0.5f*lv);
  ws[OFF_Z + o] = mu + sg*z_noise[o];
}

// ---------- causes v3: MFMA, weights resident in registers as bf16 A-fragments ----------
// block = bg*64+kk (XCD affinity: all 4 batch-groups of net kk on one XCD).
// M: gate rows packed [r:0..149 pad 160 | z pad 160 | n pad 160] = 30 tiles of 16 (+2 dummy).
// K per step: 14 chunks of 32 = [h_hi(5) | h_lo(5) | x bf16(4)].
// r/z tiles: ONE accumulator (hh+ih summed); n tiles: separate hh / ih accumulators.
__global__ void __launch_bounds__(512,2) causes3_kernel(
    const float* __restrict__ net_wih, const float* __restrict__ net_whh,
    const float* __restrict__ net_bih, const float* __restrict__ net_bhh,
    const float* __restrict__ ws, float* __restrict__ out){
  __shared__ __align__(16) u16 bF[14*16*32];   // [chunk][n=16][k=32] bf16 B-staging
  __shared__ float g_rz[320*10];               // rows r:0..159, z:160..319; stride 10 (bank-spread)
  __shared__ float g_nh[160*10];
  __shared__ float g_np[160*10];
  int kk = blockIdx.x & 63, bg = blockIdx.x >> 6, b0 = bg*8;
  int tid = threadIdx.x;
  int w = tid >> 6, lane = tid & 63, quad = lane >> 4, n16 = lane & 15;
  const float* whhk = net_whh + (size_t)kk*H3c*Hc;
  const float* wihk = net_wih + (size_t)kk*H3c*Wc;
  const float* bihk = net_bih + kk*H3c;
  const float* bhhk = net_bhh + kk*H3c;

  // ---- build resident A-fragments: A[m=lane&15][k=quad*8+j] ----
  short8 whhA[4][5], wihA[4][4];
  #pragma unroll
  for (int ti=0; ti<4; ti++){
    int tile = w*4 + ti;                 // 0..31 (30,31 dummy)
    int sec = tile/10;                   // 0=r,1=z,2=n
    int sr = (tile - sec*10)*16 + n16;   // row within section (0..159)
    bool rowok = (tile < 30) && (sr < Hc);
    int grow = sec*Hc + sr;
    #pragma unroll
    for (int c=0;c<5;c++){
      union { short8 v; u16 u[8]; } t8;
      #pragma unroll
      for (int j=0;j<8;j++){
        int k = c*32 + quad*8 + j;
        float v = (rowok && k < Hc) ? whhk[(size_t)grow*Hc + k] : 0.f;
        t8.u[j] = f2us(v);
      }
      whhA[ti][c] = t8.v;
    }
    #pragma unroll
    for (int c=0;c<4;c++){
      union { short8 v; u16 u[8]; } t8;
      #pragma unroll
      for (int j=0;j<8;j++){
        int k = c*32 + quad*8 + j;
        float v = (rowok && k < Wc) ? wihk[(size_t)grow*Wc + k] : 0.f;
        t8.u[j] = f2us(v);
      }
      wihA[ti][c] = t8.v;
    }
  }

  // ---- zero B staging (pads stay zero forever) ----
  for (int i=tid; i<14*16*32/2; i+=512) ((u32*)bF)[i] = 0u;
  __syncthreads();

  // ---- per-task state (<=3 tasks/thread), h in registers ----
  float hst[3] = {0.f,0.f,0.f};
  float brz_r[3], brz_z[3], bnh_[3], bnp_[3];
  #pragma unroll
  for (int q=0;q<3;q++){
    int task = tid + q*512;
    if (task < 1200){
      int t = task >> 3, bb = task & 7;
      float h = ws[OFF_Z + (b0+bb)*Hc + t];
      hst[q] = h;
      brz_r[q] = bhhk[t]      + bihk[t];
      brz_z[q] = bhhk[Hc+t]   + bihk[Hc+t];
      bnh_[q]  = bhhk[2*Hc+t];
      bnp_[q]  = bihk[2*Hc+t];
      u16 hi = f2us(h); float hif = us2f(hi); u16 lo = f2us(h - hif);
      bF[((t>>5)*16 + bb)*32 + (t&31)] = hi;
      bF[((5 + (t>>5))*16 + bb)*32 + (t&31)] = lo;
    }
  }
  // stage x(0) as bf16
  for (int it=tid; it<800; it+=512){
    int bb = it/100, i = it - bb*100;
    float xv = ws[OFF_WX + (b0+bb)*KWc + i];
    bF[((10 + (i>>5))*16 + bb)*32 + (i&31)] = f2us(xv);
  }

  const bool isN = (w >= 5);
  for (int s=0;s<Kc;s++){
    __syncthreads();   // B-frags ready
    floatx4 accH[4] = {{0.f,0.f,0.f,0.f},{0.f,0.f,0.f,0.f},{0.f,0.f,0.f,0.f},{0.f,0.f,0.f,0.f}};
    floatx4 accP[4] = {{0.f,0.f,0.f,0.f},{0.f,0.f,0.f,0.f},{0.f,0.f,0.f,0.f},{0.f,0.f,0.f,0.f}};
    const u16* bBase = bF + (size_t)n16*32 + (size_t)quad*8;   // B[k=quad*8+j][n=lane&15]
    short8 bcur = *(const short8*)bBase;
    #pragma unroll
    for (int c=0;c<14;c++){
      short8 bnext = bcur;
      if (c<13) bnext = *(const short8*)(bBase + (size_t)(c+1)*512);
      short8 b = bcur;
      if (c < 10){
        int ca = (c<5)? c : (c-5);      // hh hi / hh lo reuse same A
        #pragma unroll
        for (int ti=0;ti<4;ti++)
          accH[ti] = __builtin_amdgcn_mfma_f32_16x16x32_bf16(whhA[ti][ca], b, accH[ti], 0,0,0);
      } else {
        int ca = c-10;
        if (isN){
          #pragma unroll
          for (int ti=0;ti<4;ti++)
            accP[ti] = __builtin_amdgcn_mfma_f32_16x16x32_bf16(wihA[ti][ca], b, accP[ti], 0,0,0);
        } else {
          #pragma unroll
          for (int ti=0;ti<4;ti++)
            accH[ti] = __builtin_amdgcn_mfma_f32_16x16x32_bf16(wihA[ti][ca], b, accH[ti], 0,0,0);
        }
      }
      bcur = bnext;
    }
    // C -> LDS   (C layout: n=lane&15, m=quad*4+reg)
    if (n16 < 8){
      #pragma unroll
      for (int ti=0;ti<4;ti++){
        int tile = w*4 + ti;
        if (tile < 30){
          int sec = tile/10;
          int srb = (tile - sec*10)*16 + quad*4;
          if (sec < 2){
            float* gp = g_rz + (sec*160 + srb)*10 + n16;
            #pragma unroll
            for (int r=0;r<4;r++) gp[r*10] = accH[ti][r];
          } else {
            float* gh = g_nh + srb*10 + n16;
            float* gq = g_np + srb*10 + n16;
            #pragma unroll
            for (int r=0;r<4;r++){ gh[r*10] = accH[ti][r]; gq[r*10] = accP[ti][r]; }
          }
        }
      }
    }
    __syncthreads();   // gates ready; bF reads done -> safe to overwrite
    #pragma unroll
    for (int q=0;q<3;q++){
      int task = tid + q*512;
      if (task < 1200){
        int t = task >> 3, bb = task & 7;
        float a_r = g_rz[t*10+bb] + brz_r[q];
        float a_z = g_rz[(160+t)*10+bb] + brz_z[q];
        float r  = 1.f/(1.f+__expf(-a_r));
        float zz = 1.f/(1.f+__expf(-a_z));
        float nx = (g_np[t*10+bb] + bnp_[q]) + r*(g_nh[t*10+bb] + bnh_[q]);
        nx = fminf(fmaxf(nx,-15.f),15.f);
        float e2 = __expf(2.f*nx);
        float n = (e2-1.f)/(e2+1.f);
        float h = (1.f-zz)*n + zz*hst[q];
        hst[q] = h;
        u16 hi = f2us(h); float hif = us2f(hi); u16 lo = f2us(h - hif);
        bF[((t>>5)*16 + bb)*32 + (t&31)] = hi;
        bF[((5 + (t>>5))*16 + bb)*32 + (t&31)] = lo;
      }
    }
    if (s < Kc-1){
      for (int it=tid; it<800; it+=512){
        int bb = it/100, i = it - bb*100;
        float xv = ws[OFF_WX + (b0+bb)*KWc + (s+1)*Wc + i];
        bF[((10 + (i>>5))*16 + bb)*32 + (i&31)] = f2us(xv);
      }
    }
  }
  #pragma unroll
  for (int q=0;q<3;q++){
    int task = tid + q*512;
    if (task < 1200){
      int t = task >> 3, bb = task & 7;
      out[((size_t)(b0+bb)*Kc + kk)*Hc + t] = hst[q];
    }
  }
}

extern "C" void kernel_launch(void* const* d_in, const int* in_sizes, int n_in,
                              void* d_out, int out_size, void* d_ws, size_t ws_size,
                              hipStream_t stream){
  const float* x        = (const float*)d_in[0];
  const float* y        = (const float*)d_in[1];
  const float* z_noise  = (const float*)d_in[2];
  const float* lin_w    = (const float*)d_in[3];
  const float* lin_b    = (const float*)d_in[4];
  const float* a        = (const float*)d_in[5];
  const float* bias     = (const float*)d_in[6];
  const float* gl_wih   = (const float*)d_in[7];
  const float* gl_whh   = (const float*)d_in[8];
  const float* gl_bih   = (const float*)d_in[9];
  const float* gl_bhh   = (const float*)d_in[10];
  const float* mu_w     = (const float*)d_in[11];
  const float* mu_b     = (const float*)d_in[12];
  const float* std_w    = (const float*)d_in[13];
  const float* std_b    = (const float*)d_in[14];
  const float* net_wih  = (const float*)d_in[15];
  const float* net_whh  = (const float*)d_in[16];
  const float* net_bih  = (const float*)d_in[17];
  const float* net_bhh  = (const float*)d_in[18];
  float* ws = (float*)d_ws;
  float* out = (float*)d_out;

  wx_kernel<<<(Bc*KWc+255)/256, 256, 0, stream>>>(x, lin_w, lin_b, ws);
  attn_kernel<<<Bc*Kc, 256, 0, stream>>>(y, a, bias, ws);
  glproj_kernel<<<(Kc*Bc*H3c+255)/256, 256, 0, stream>>>(gl_wih, gl_bih, ws);
  glgru_kernel<<<Bc, 512, 0, stream>>>(gl_whh, gl_bhh, ws);
  z_kernel<<<(Bc*Hc+255)/256, 256, 0, stream>>>(z_noise, mu_w, mu_b, std_w, std_b, ws);
  causes3_kernel<<<Kc*4, 512, 0, stream>>>(net_wih, net_whh, net_bih, net_bhh, ws, out);
}

// Round 6
// 677.551 us; speedup vs baseline: 19.7966x; 1.1624x over previous
//
#include <hip/hip_runtime.h>

#define Bc 32
#define Kc 64
#define Wc 100
#define Hc 150
#define H3c 450
#define KWc 6400
#define ALPHAc 0.2f
#define THRESc 0.0002f

typedef unsigned int u32;
typedef unsigned short u16;
typedef __attribute__((ext_vector_type(8))) short short8;   // 8 bf16
typedef __attribute__((ext_vector_type(4))) float floatx4;  // 4 f32 acc

// ---- ws layout (float offsets), 4.55 MB ----
#define OFF_WX      0u          // 204800  Wx (B,K,W) fp32
#define OFF_CS      204800u     // 2048    causesum (B,K)
#define OFF_GX      206848u     // 921600  gl proj (s,b,g)
#define OFF_HT      1128448u    // 4800    h_t (B,H)
#define OFF_Z       1133248u    // 4800    z (B,H)

__device__ __forceinline__ float us2f(u16 u){ u32 x=((u32)u)<<16; return __uint_as_float(x); }
__device__ __forceinline__ u16 f2us(float f){
  u32 x = __float_as_uint(f);
  u32 r = (x + 0x7fffu + ((x>>16)&1u)) >> 16;   // RNE bf16
  return (u16)r;
}

// ---------- Wx = x @ lin_w.T + lin_b ----------
__global__ void wx_kernel(const float* __restrict__ x, const float* __restrict__ lin_w,
                          const float* __restrict__ lin_b, float* __restrict__ ws){
  int o = blockIdx.x*256 + threadIdx.x;
  if (o >= Bc*KWc) return;
  int i = o % Wc;
  int bk = o / Wc;
  const float4* xr = (const float4*)(x + bk*Wc);
  const float4* wr = (const float4*)(lin_w + i*Wc);
  float acc = lin_b[i];
  #pragma unroll
  for (int j=0;j<25;j++){
    float4 xv = xr[j], wv = wr[j];
    acc += xv.x*wv.x + xv.y*wv.y + xv.z*wv.z + xv.w*wv.w;
  }
  ws[OFF_WX + o] = acc;
}

// ---------- attention softmax + thresholded sum ----------
__global__ void attn_kernel(const float* __restrict__ y, const float* __restrict__ a,
                            const float* __restrict__ bias, float* __restrict__ ws){
  __shared__ float e_l[KWc];
  __shared__ float red[4];
  int row = blockIdx.x;          // b*64 + k
  int b = row >> 6, k = row & 63;
  int tid = threadIdx.x;
  float a0 = a[0], a1 = a[1];
  float yv = y[row];
  const float* v = ws + OFF_WX + b*KWc;
  const float* br = bias + k*KWc;
  float m = -3.4e38f;
  for (int j=tid; j<KWc; j+=256){
    float e = a0*yv + a1*v[j] + br[j];
    e = (e >= 0.f) ? e : ALPHAc*e;
    e_l[j] = e;
    m = fmaxf(m, e);
  }
  for (int o=32;o;o>>=1) m = fmaxf(m, __shfl_down(m, o));
  if ((tid&63)==0) red[tid>>6] = m;
  __syncthreads();
  m = fmaxf(fmaxf(red[0],red[1]), fmaxf(red[2],red[3]));
  __syncthreads();
  float ssum = 0.f;
  for (int j=tid; j<KWc; j+=256){
    float ex = expf(e_l[j]-m);
    e_l[j] = ex;
    ssum += ex;
  }
  for (int o=32;o;o>>=1) ssum += __shfl_down(ssum, o);
  if ((tid&63)==0) red[tid>>6] = ssum;
  __syncthreads();
  float s = red[0]+red[1]+red[2]+red[3];
  __syncthreads();
  float cs = 0.f;
  for (int j=tid; j<KWc; j+=256){
    float att = e_l[j] / s;
    if (att >= THRESc) cs += v[j];
  }
  for (int o=32;o;o>>=1) cs += __shfl_down(cs, o);
  if ((tid&63)==0) red[tid>>6] = cs;
  __syncthreads();
  if (tid==0) ws[OFF_CS + row] = red[0]+red[1]+red[2]+red[3];
}

// ---------- gl input projection ----------
__global__ void glproj_kernel(const float* __restrict__ gl_wih, const float* __restrict__ gl_bih,
                              float* __restrict__ ws){
  int o = blockIdx.x*256 + threadIdx.x;
  if (o >= Kc*Bc*H3c) return;
  int g = o % H3c;
  int t = o / H3c;               // s*32 + b
  int b = t & 31, s = t >> 5;
  float cs = ws[OFF_CS + b*Kc + s];
  const float4* xr = (const float4*)(ws + OFF_WX + b*KWc + s*Wc);
  const float4* wr = (const float4*)(gl_wih + g*Wc);
  float acc = gl_bih[g];
  #pragma unroll
  for (int j=0;j<25;j++){
    float4 wv = wr[j], xv = xr[j];
    acc += (xv.x+cs)*wv.x + (xv.y+cs)*wv.y + (xv.z+cs)*wv.z + (xv.w+cs)*wv.w;
  }
  ws[OFF_GX + o] = acc;
}

// ---------- gl recurrent GRU v4: MFMA, 2 blocks x 16 batches ----------
// M: [r pad160 | z pad160 | n pad160] = 30 tiles of 16 (+2 dummy).
// K: 10 chunks of 32 = h_hi(5) | h_lo(5). gx (incl. bih) precomputed by glproj.
__global__ void __launch_bounds__(512,1) glgru4_kernel(
    const float* __restrict__ gl_whh, const float* __restrict__ gl_bhh,
    float* __restrict__ ws){
  __shared__ __align__(16) u16 bF[10*16*32];   // [chunk][n=16][k=32]
  __shared__ float g_l[480*17];                // padded gate rows x 16 batches, stride 17
  int b0 = blockIdx.x*16;
  int tid = threadIdx.x;
  int w = tid >> 6, lane = tid & 63, quad = lane >> 4, n16 = lane & 15;

  // ---- resident A-fragments: A[m=lane&15][k=quad*8+j], bf16 ----
  short8 whhA[4][5];
  #pragma unroll
  for (int ti=0; ti<4; ti++){
    int tile = w*4 + ti;                 // 0..31 (30,31 dummy)
    int sec = tile/10;                   // 0=r,1=z,2=n
    int sr = (tile - sec*10)*16 + n16;   // row within 160-padded section
    bool rowok = (tile < 30) && (sr < Hc);
    int grow = sec*Hc + sr;
    #pragma unroll
    for (int c=0;c<5;c++){
      union { short8 v; u16 u[8]; } t8;
      #pragma unroll
      for (int j=0;j<8;j++){
        int k = c*32 + quad*8 + j;
        float v = (rowok && k < Hc) ? gl_whh[(size_t)grow*Hc + k] : 0.f;
        t8.u[j] = f2us(v);
      }
      whhA[ti][c] = t8.v;
    }
  }
  // zero B staging (k-pads stay zero; h0 = 0)
  for (int i=tid; i<10*512/2; i+=512) ((u32*)bF)[i] = 0u;

  // ---- per-task state: task = t*16 + b_local, 2400 tasks, <=5/thread ----
  float hst[5] = {0.f,0.f,0.f,0.f,0.f};
  float bh_r[5], bh_z[5], bh_n[5];
  #pragma unroll
  for (int q=0;q<5;q++){
    int task = tid + q*512;
    if (task < 2400){
      int t = task >> 4;
      bh_r[q] = gl_bhh[t];
      bh_z[q] = gl_bhh[Hc+t];
      bh_n[q] = gl_bhh[2*Hc+t];
    }
  }

  for (int s=0;s<Kc;s++){
    __syncthreads();   // bF ready
    // prefetch gx (overlaps MFMA)
    float gxr[5], gxz[5], gxn[5];
    const float* gxb = ws + OFF_GX + (size_t)(s*Bc)*H3c;
    #pragma unroll
    for (int q=0;q<5;q++){
      int task = tid + q*512;
      if (task < 2400){
        int t = task >> 4, bl = task & 15;
        const float* gp = gxb + (size_t)(b0+bl)*H3c;
        gxr[q] = gp[t]; gxz[q] = gp[Hc+t]; gxn[q] = gp[2*Hc+t];
      }
    }
    // MFMA stage
    floatx4 acc[4] = {{0.f,0.f,0.f,0.f},{0.f,0.f,0.f,0.f},{0.f,0.f,0.f,0.f},{0.f,0.f,0.f,0.f}};
    const u16* bBase = bF + (size_t)n16*32 + (size_t)quad*8;
    #pragma unroll
    for (int c=0;c<10;c++){
      short8 b8 = *(const short8*)(bBase + (size_t)c*512);
      int ca = (c<5)? c : (c-5);
      #pragma unroll
      for (int ti=0;ti<4;ti++)
        acc[ti] = __builtin_amdgcn_mfma_f32_16x16x32_bf16(whhA[ti][ca], b8, acc[ti], 0,0,0);
    }
    // C -> LDS (C layout: col=lane&15, row=quad*4+reg)
    #pragma unroll
    for (int ti=0;ti<4;ti++){
      int tile = w*4 + ti;
      if (tile < 30){
        int row0 = tile*16 + quad*4;
        float* gp = g_l + row0*17 + n16;
        #pragma unroll
        for (int r=0;r<4;r++) gp[r*17] = acc[ti][r];
      }
    }
    __syncthreads();   // gates ready; bF MFMA reads done
    #pragma unroll
    for (int q=0;q<5;q++){
      int task = tid + q*512;
      if (task < 2400){
        int t = task >> 4, bl = task & 15;
        float a_r = gxr[q] + g_l[t*17+bl] + bh_r[q];
        float a_z = gxz[q] + g_l[(160+t)*17+bl] + bh_z[q];
        float r  = 1.f/(1.f+__expf(-a_r));
        float zz = 1.f/(1.f+__expf(-a_z));
        float nx = gxn[q] + r*(g_l[(320+t)*17+bl] + bh_n[q]);
        nx = fminf(fmaxf(nx,-15.f),15.f);
        float e2 = __expf(2.f*nx);
        float n = (e2-1.f)/(e2+1.f);
        float h = (1.f-zz)*n + zz*hst[q];
        hst[q] = h;
        u16 hi = f2us(h); float hif = us2f(hi); u16 lo = f2us(h - hif);
        bF[(t>>5)*512 + bl*32 + (t&31)] = hi;
        bF[(5+(t>>5))*512 + bl*32 + (t&31)] = lo;
      }
    }
  }
  #pragma unroll
  for (int q=0;q<5;q++){
    int task = tid + q*512;
    if (task < 2400){
      int t = task >> 4, bl = task & 15;
      ws[OFF_HT + (size_t)(b0+bl)*Hc + t] = hst[q];
    }
  }
}

// ---------- z = mu + sigma * z_noise ----------
__global__ void z_kernel(const float* __restrict__ z_noise, const float* __restrict__ mu_w,
                         const float* __restrict__ mu_b, const float* __restrict__ std_w,
                         const float* __restrict__ std_b, float* __restrict__ ws){
  int o = blockIdx.x*256 + threadIdx.x;
  if (o >= Bc*Hc) return;
  int t = o % Hc, b = o / Hc;
  const float* h = ws + OFF_HT + b*Hc;
  const float2* mwr = (const float2*)(mu_w + t*Hc);
  const float2* swr = (const float2*)(std_w + t*Hc);
  float mu = mu_b[t], lv = std_b[t];
  for (int j=0;j<Hc/2;j++){
    float2 mw = mwr[j], sw = swr[j];
    float h0 = h[2*j], h1 = h[2*j+1];
    mu += h0*mw.x + h1*mw.y;
    lv += h0*sw.x + h1*sw.y;
  }
  float sg = expf(0.5f*lv);
  ws[OFF_Z + o] = mu + sg*z_noise[o];
}

// ---------- causes v3: MFMA, weights resident in registers as bf16 A-fragments ----------
__global__ void __launch_bounds__(512,2) causes3_kernel(
    const float* __restrict__ net_wih, const float* __restrict__ net_whh,
    const float* __restrict__ net_bih, const float* __restrict__ net_bhh,
    const float* __restrict__ ws, float* __restrict__ out){
  __shared__ __align__(16) u16 bF[14*16*32];   // [chunk][n=16][k=32] bf16 B-staging
  __shared__ float g_rz[320*10];
  __shared__ float g_nh[160*10];
  __shared__ float g_np[160*10];
  int kk = blockIdx.x & 63, bg = blockIdx.x >> 6, b0 = bg*8;
  int tid = threadIdx.x;
  int w = tid >> 6, lane = tid & 63, quad = lane >> 4, n16 = lane & 15;
  const float* whhk = net_whh + (size_t)kk*H3c*Hc;
  const float* wihk = net_wih + (size_t)kk*H3c*Wc;
  const float* bihk = net_bih + kk*H3c;
  const float* bhhk = net_bhh + kk*H3c;

  short8 whhA[4][5], wihA[4][4];
  #pragma unroll
  for (int ti=0; ti<4; ti++){
    int tile = w*4 + ti;
    int sec = tile/10;
    int sr = (tile - sec*10)*16 + n16;
    bool rowok = (tile < 30) && (sr < Hc);
    int grow = sec*Hc + sr;
    #pragma unroll
    for (int c=0;c<5;c++){
      union { short8 v; u16 u[8]; } t8;
      #pragma unroll
      for (int j=0;j<8;j++){
        int k = c*32 + quad*8 + j;
        float v = (rowok && k < Hc) ? whhk[(size_t)grow*Hc + k] : 0.f;
        t8.u[j] = f2us(v);
      }
      whhA[ti][c] = t8.v;
    }
    #pragma unroll
    for (int c=0;c<4;c++){
      union { short8 v; u16 u[8]; } t8;
      #pragma unroll
      for (int j=0;j<8;j++){
        int k = c*32 + quad*8 + j;
        float v = (rowok && k < Wc) ? wihk[(size_t)grow*Wc + k] : 0.f;
        t8.u[j] = f2us(v);
      }
      wihA[ti][c] = t8.v;
    }
  }

  for (int i=tid; i<14*16*32/2; i+=512) ((u32*)bF)[i] = 0u;
  __syncthreads();

  float hst[3] = {0.f,0.f,0.f};
  float brz_r[3], brz_z[3], bnh_[3], bnp_[3];
  #pragma unroll
  for (int q=0;q<3;q++){
    int task = tid + q*512;
    if (task < 1200){
      int t = task >> 3, bb = task & 7;
      float h = ws[OFF_Z + (b0+bb)*Hc + t];
      hst[q] = h;
      brz_r[q] = bhhk[t]      + bihk[t];
      brz_z[q] = bhhk[Hc+t]   + bihk[Hc+t];
      bnh_[q]  = bhhk[2*Hc+t];
      bnp_[q]  = bihk[2*Hc+t];
      u16 hi = f2us(h); float hif = us2f(hi); u16 lo = f2us(h - hif);
      bF[((t>>5)*16 + bb)*32 + (t&31)] = hi;
      bF[((5 + (t>>5))*16 + bb)*32 + (t&31)] = lo;
    }
  }
  for (int it=tid; it<800; it+=512){
    int bb = it/100, i = it - bb*100;
    float xv = ws[OFF_WX + (b0+bb)*KWc + i];
    bF[((10 + (i>>5))*16 + bb)*32 + (i&31)] = f2us(xv);
  }

  const bool isN = (w >= 5);
  for (int s=0;s<Kc;s++){
    __syncthreads();
    floatx4 accH[4] = {{0.f,0.f,0.f,0.f},{0.f,0.f,0.f,0.f},{0.f,0.f,0.f,0.f},{0.f,0.f,0.f,0.f}};
    floatx4 accP[4] = {{0.f,0.f,0.f,0.f},{0.f,0.f,0.f,0.f},{0.f,0.f,0.f,0.f},{0.f,0.f,0.f,0.f}};
    const u16* bBase = bF + (size_t)n16*32 + (size_t)quad*8;
    short8 bcur = *(const short8*)bBase;
    #pragma unroll
    for (int c=0;c<14;c++){
      short8 bnext = bcur;
      if (c<13) bnext = *(const short8*)(bBase + (size_t)(c+1)*512);
      short8 b = bcur;
      if (c < 10){
        int ca = (c<5)? c : (c-5);
        #pragma unroll
        for (int ti=0;ti<4;ti++)
          accH[ti] = __builtin_amdgcn_mfma_f32_16x16x32_bf16(whhA[ti][ca], b, accH[ti], 0,0,0);
      } else {
        int ca = c-10;
        if (isN){
          #pragma unroll
          for (int ti=0;ti<4;ti++)
            accP[ti] = __builtin_amdgcn_mfma_f32_16x16x32_bf16(wihA[ti][ca], b, accP[ti], 0,0,0);
        } else {
          #pragma unroll
          for (int ti=0;ti<4;ti++)
            accH[ti] = __builtin_amdgcn_mfma_f32_16x16x32_bf16(wihA[ti][ca], b, accH[ti], 0,0,0);
        }
      }
      bcur = bnext;
    }
    if (n16 < 8){
      #pragma unroll
      for (int ti=0;ti<4;ti++){
        int tile = w*4 + ti;
        if (tile < 30){
          int sec = tile/10;
          int srb = (tile - sec*10)*16 + quad*4;
          if (sec < 2){
            float* gp = g_rz + (sec*160 + srb)*10 + n16;
            #pragma unroll
            for (int r=0;r<4;r++) gp[r*10] = accH[ti][r];
          } else {
            float* gh = g_nh + srb*10 + n16;
            float* gq = g_np + srb*10 + n16;
            #pragma unroll
            for (int r=0;r<4;r++){ gh[r*10] = accH[ti][r]; gq[r*10] = accP[ti][r]; }
          }
        }
      }
    }
    __syncthreads();
    #pragma unroll
    for (int q=0;q<3;q++){
      int task = tid + q*512;
      if (task < 1200){
        int t = task >> 3, bb = task & 7;
        float a_r = g_rz[t*10+bb] + brz_r[q];
        float a_z = g_rz[(160+t)*10+bb] + brz_z[q];
        float r  = 1.f/(1.f+__expf(-a_r));
        float zz = 1.f/(1.f+__expf(-a_z));
        float nx = (g_np[t*10+bb] + bnp_[q]) + r*(g_nh[t*10+bb] + bnh_[q]);
        nx = fminf(fmaxf(nx,-15.f),15.f);
        float e2 = __expf(2.f*nx);
        float n = (e2-1.f)/(e2+1.f);
        float h = (1.f-zz)*n + zz*hst[q];
        hst[q] = h;
        u16 hi = f2us(h); float hif = us2f(hi); u16 lo = f2us(h - hif);
        bF[((t>>5)*16 + bb)*32 + (t&31)] = hi;
        bF[((5 + (t>>5))*16 + bb)*32 + (t&31)] = lo;
      }
    }
    if (s < Kc-1){
      for (int it=tid; it<800; it+=512){
        int bb = it/100, i = it - bb*100;
        float xv = ws[OFF_WX + (b0+bb)*KWc + (s+1)*Wc + i];
        bF[((10 + (i>>5))*16 + bb)*32 + (i&31)] = f2us(xv);
      }
    }
  }
  #pragma unroll
  for (int q=0;q<3;q++){
    int task = tid + q*512;
    if (task < 1200){
      int t = task >> 3, bb = task & 7;
      out[((size_t)(b0+bb)*Kc + kk)*Hc + t] = hst[q];
    }
  }
}

extern "C" void kernel_launch(void* const* d_in, const int* in_sizes, int n_in,
                              void* d_out, int out_size, void* d_ws, size_t ws_size,
                              hipStream_t stream){
  const float* x        = (const float*)d_in[0];
  const float* y        = (const float*)d_in[1];
  const float* z_noise  = (const float*)d_in[2];
  const float* lin_w    = (const float*)d_in[3];
  const float* lin_b    = (const float*)d_in[4];
  const float* a        = (const float*)d_in[5];
  const float* bias     = (const float*)d_in[6];
  const float* gl_wih   = (const float*)d_in[7];
  const float* gl_whh   = (const float*)d_in[8];
  const float* gl_bih   = (const float*)d_in[9];
  const float* gl_bhh   = (const float*)d_in[10];
  const float* mu_w     = (const float*)d_in[11];
  const float* mu_b     = (const float*)d_in[12];
  const float* std_w    = (const float*)d_in[13];
  const float* std_b    = (const float*)d_in[14];
  const float* net_wih  = (const float*)d_in[15];
  const float* net_whh  = (const float*)d_in[16];
  const float* net_bih  = (const float*)d_in[17];
  const float* net_bhh  = (const float*)d_in[18];
  float* ws = (float*)d_ws;
  float* out = (float*)d_out;

  wx_kernel<<<(Bc*KWc+255)/256, 256, 0, stream>>>(x, lin_w, lin_b, ws);
  attn_kernel<<<Bc*Kc, 256, 0, stream>>>(y, a, bias, ws);
  glproj_kernel<<<(Kc*Bc*H3c+255)/256, 256, 0, stream>>>(gl_wih, gl_bih, ws);
  glgru4_kernel<<<2, 512, 0, stream>>>(gl_whh, gl_bhh, ws);
  z_kernel<<<(Bc*Hc+255)/256, 256, 0, stream>>>(z_noise, mu_w, mu_b, std_w, std_b, ws);
  causes3_kernel<<<Kc*4, 512, 0, stream>>>(net_wih, net_whh, net_bih, net_bhh, ws, out);
}

// Round 7
// 589.953 us; speedup vs baseline: 22.7361x; 1.1485x over previous
//
#include <hip/hip_runtime.h>

#define Bc 32
#define Kc 64
#define Wc 100
#define Hc 150
#define H3c 450
#define KWc 6400
#define ALPHAc 0.2f
#define THRESc 0.0002f

typedef unsigned int u32;
typedef unsigned short u16;
typedef __attribute__((ext_vector_type(8))) short short8;   // 8 bf16
typedef __attribute__((ext_vector_type(4))) float floatx4;  // 4 f32 acc

// ---- ws layout (float offsets), 4.55 MB ----
#define OFF_WX      0u          // 204800  Wx (B,K,W) fp32
#define OFF_CS      204800u     // 2048    causesum (B,K)
#define OFF_GX      206848u     // 921600  gl proj (s,b,g)
#define OFF_HT      1128448u    // 4800    h_t (B,H)
#define OFF_Z       1133248u    // 4800    z (B,H)

__device__ __forceinline__ float us2f(u16 u){ u32 x=((u32)u)<<16; return __uint_as_float(x); }
__device__ __forceinline__ u16 f2us(float f){
  u32 x = __float_as_uint(f);
  u32 r = (x + 0x7fffu + ((x>>16)&1u)) >> 16;   // RNE bf16
  return (u16)r;
}

// ---------- Wx = x @ lin_w.T + lin_b ----------
__global__ void wx_kernel(const float* __restrict__ x, const float* __restrict__ lin_w,
                          const float* __restrict__ lin_b, float* __restrict__ ws){
  int o = blockIdx.x*256 + threadIdx.x;
  if (o >= Bc*KWc) return;
  int i = o % Wc;
  int bk = o / Wc;
  const float4* xr = (const float4*)(x + bk*Wc);
  const float4* wr = (const float4*)(lin_w + i*Wc);
  float acc = lin_b[i];
  #pragma unroll
  for (int j=0;j<25;j++){
    float4 xv = xr[j], wv = wr[j];
    acc += xv.x*wv.x + xv.y*wv.y + xv.z*wv.z + xv.w*wv.w;
  }
  ws[OFF_WX + o] = acc;
}

// ---------- attention softmax + thresholded sum ----------
__global__ void attn_kernel(const float* __restrict__ y, const float* __restrict__ a,
                            const float* __restrict__ bias, float* __restrict__ ws){
  __shared__ float e_l[KWc];
  __shared__ float red[4];
  int row = blockIdx.x;          // b*64 + k
  int b = row >> 6, k = row & 63;
  int tid = threadIdx.x;
  float a0 = a[0], a1 = a[1];
  float yv = y[row];
  const float* v = ws + OFF_WX + b*KWc;
  const float* br = bias + k*KWc;
  float m = -3.4e38f;
  for (int j=tid; j<KWc; j+=256){
    float e = a0*yv + a1*v[j] + br[j];
    e = (e >= 0.f) ? e : ALPHAc*e;
    e_l[j] = e;
    m = fmaxf(m, e);
  }
  for (int o=32;o;o>>=1) m = fmaxf(m, __shfl_down(m, o));
  if ((tid&63)==0) red[tid>>6] = m;
  __syncthreads();
  m = fmaxf(fmaxf(red[0],red[1]), fmaxf(red[2],red[3]));
  __syncthreads();
  float ssum = 0.f;
  for (int j=tid; j<KWc; j+=256){
    float ex = expf(e_l[j]-m);
    e_l[j] = ex;
    ssum += ex;
  }
  for (int o=32;o;o>>=1) ssum += __shfl_down(ssum, o);
  if ((tid&63)==0) red[tid>>6] = ssum;
  __syncthreads();
  float s = red[0]+red[1]+red[2]+red[3];
  __syncthreads();
  float cs = 0.f;
  for (int j=tid; j<KWc; j+=256){
    float att = e_l[j] / s;
    if (att >= THRESc) cs += v[j];
  }
  for (int o=32;o;o>>=1) cs += __shfl_down(cs, o);
  if ((tid&63)==0) red[tid>>6] = cs;
  __syncthreads();
  if (tid==0) ws[OFF_CS + row] = red[0]+red[1]+red[2]+red[3];
}

// ---------- gl input projection ----------
__global__ void glproj_kernel(const float* __restrict__ gl_wih, const float* __restrict__ gl_bih,
                              float* __restrict__ ws){
  int o = blockIdx.x*256 + threadIdx.x;
  if (o >= Kc*Bc*H3c) return;
  int g = o % H3c;
  int t = o / H3c;               // s*32 + b
  int b = t & 31, s = t >> 5;
  float cs = ws[OFF_CS + b*Kc + s];
  const float4* xr = (const float4*)(ws + OFF_WX + b*KWc + s*Wc);
  const float4* wr = (const float4*)(gl_wih + g*Wc);
  float acc = gl_bih[g];
  #pragma unroll
  for (int j=0;j<25;j++){
    float4 wv = wr[j], xv = xr[j];
    acc += (xv.x+cs)*wv.x + (xv.y+cs)*wv.y + (xv.z+cs)*wv.z + (xv.w+cs)*wv.w;
  }
  ws[OFF_GX + o] = acc;
}

// ---------- gl recurrent GRU v4: MFMA, 2 blocks x 16 batches ----------
// task decomposition: tau = tid + q*512 in [0,2400); bl = tau/150, t = tau%150
// -> lane-adjacent threads walk consecutive t => coalesced gx/bias/out traffic.
__global__ void __launch_bounds__(512,1) glgru4_kernel(
    const float* __restrict__ gl_whh, const float* __restrict__ gl_bhh,
    float* __restrict__ ws){
  __shared__ __align__(16) u16 bF[10*16*32];   // [chunk][n=16][k=32]
  __shared__ float g_l[480*17];                // gate rows x 16 batches, stride 17
  int b0 = blockIdx.x*16;
  int tid = threadIdx.x;
  int w = tid >> 6, lane = tid & 63, quad = lane >> 4, n16 = lane & 15;

  // ---- resident A-fragments: A[m=lane&15][k=quad*8+j], bf16 ----
  short8 whhA[4][5];
  #pragma unroll
  for (int ti=0; ti<4; ti++){
    int tile = w*4 + ti;                 // 0..31 (30,31 dummy)
    int sec = tile/10;                   // 0=r,1=z,2=n
    int sr = (tile - sec*10)*16 + n16;   // row within 160-padded section
    bool rowok = (tile < 30) && (sr < Hc);
    int grow = sec*Hc + sr;
    #pragma unroll
    for (int c=0;c<5;c++){
      union { short8 v; u16 u[8]; } t8;
      #pragma unroll
      for (int j=0;j<8;j++){
        int k = c*32 + quad*8 + j;
        float v = (rowok && k < Hc) ? gl_whh[(size_t)grow*Hc + k] : 0.f;
        t8.u[j] = f2us(v);
      }
      whhA[ti][c] = t8.v;
    }
  }
  // zero B staging (k-pads stay zero; h0 = 0)
  for (int i=tid; i<10*512/2; i+=512) ((u32*)bF)[i] = 0u;

  // ---- per-task state: 2400 tasks, <=5/thread, bl = tau/150, t = tau%150 ----
  float hst[5] = {0.f,0.f,0.f,0.f,0.f};
  float bh_r[5], bh_z[5], bh_n[5];
  int tT[5], tBL[5];
  #pragma unroll
  for (int q=0;q<5;q++){
    int task = tid + q*512;
    if (task < 2400){
      int bl = task/150, t = task - bl*150;
      tT[q] = t; tBL[q] = bl;
      bh_r[q] = gl_bhh[t];
      bh_z[q] = gl_bhh[Hc+t];
      bh_n[q] = gl_bhh[2*Hc+t];
    } else { tT[q] = 0; tBL[q] = -1; }
  }

  for (int s=0;s<Kc;s++){
    __syncthreads();   // bF ready
    // prefetch gx, coalesced in t (overlaps MFMA)
    float gxr[5], gxz[5], gxn[5];
    const float* gxb = ws + OFF_GX + (size_t)(s*Bc)*H3c;
    #pragma unroll
    for (int q=0;q<5;q++){
      if (tBL[q] >= 0){
        const float* gp = gxb + (size_t)(b0+tBL[q])*H3c;
        int t = tT[q];
        gxr[q] = gp[t]; gxz[q] = gp[Hc+t]; gxn[q] = gp[2*Hc+t];
      }
    }
    // MFMA stage
    floatx4 acc[4] = {{0.f,0.f,0.f,0.f},{0.f,0.f,0.f,0.f},{0.f,0.f,0.f,0.f},{0.f,0.f,0.f,0.f}};
    const u16* bBase = bF + (size_t)n16*32 + (size_t)quad*8;
    #pragma unroll
    for (int c=0;c<10;c++){
      short8 b8 = *(const short8*)(bBase + (size_t)c*512);
      int ca = (c<5)? c : (c-5);
      #pragma unroll
      for (int ti=0;ti<4;ti++)
        acc[ti] = __builtin_amdgcn_mfma_f32_16x16x32_bf16(whhA[ti][ca], b8, acc[ti], 0,0,0);
    }
    // C -> LDS (C layout: col=lane&15, row=quad*4+reg)
    #pragma unroll
    for (int ti=0;ti<4;ti++){
      int tile = w*4 + ti;
      if (tile < 30){
        int row0 = tile*16 + quad*4;
        float* gp = g_l + row0*17 + n16;
        #pragma unroll
        for (int r=0;r<4;r++) gp[r*17] = acc[ti][r];
      }
    }
    __syncthreads();   // gates ready; bF MFMA reads done
    #pragma unroll
    for (int q=0;q<5;q++){
      if (tBL[q] >= 0){
        int t = tT[q], bl = tBL[q];
        float a_r = gxr[q] + g_l[t*17+bl] + bh_r[q];
        float a_z = gxz[q] + g_l[(160+t)*17+bl] + bh_z[q];
        float r  = 1.f/(1.f+__expf(-a_r));
        float zz = 1.f/(1.f+__expf(-a_z));
        float nx = gxn[q] + r*(g_l[(320+t)*17+bl] + bh_n[q]);
        nx = fminf(fmaxf(nx,-15.f),15.f);
        float e2 = __expf(2.f*nx);
        float n = (e2-1.f)/(e2+1.f);
        float h = (1.f-zz)*n + zz*hst[q];
        hst[q] = h;
        u16 hi = f2us(h); float hif = us2f(hi); u16 lo = f2us(h - hif);
        bF[(t>>5)*512 + bl*32 + (t&31)] = hi;
        bF[(5+(t>>5))*512 + bl*32 + (t&31)] = lo;
      }
    }
  }
  #pragma unroll
  for (int q=0;q<5;q++){
    if (tBL[q] >= 0)
      ws[OFF_HT + (size_t)(b0+tBL[q])*Hc + tT[q]] = hst[q];
  }
}

// ---------- z = mu + sigma * z_noise ----------
__global__ void z_kernel(const float* __restrict__ z_noise, const float* __restrict__ mu_w,
                         const float* __restrict__ mu_b, const float* __restrict__ std_w,
                         const float* __restrict__ std_b, float* __restrict__ ws){
  int o = blockIdx.x*256 + threadIdx.x;
  if (o >= Bc*Hc) return;
  int t = o % Hc, b = o / Hc;
  const float* h = ws + OFF_HT + b*Hc;
  const float2* mwr = (const float2*)(mu_w + t*Hc);
  const float2* swr = (const float2*)(std_w + t*Hc);
  float mu = mu_b[t], lv = std_b[t];
  for (int j=0;j<Hc/2;j++){
    float2 mw = mwr[j], sw = swr[j];
    float h0 = h[2*j], h1 = h[2*j+1];
    mu += h0*mw.x + h1*mw.y;
    lv += h0*sw.x + h1*sw.y;
  }
  float sg = expf(0.5f*lv);
  ws[OFF_Z + o] = mu + sg*z_noise[o];
}

// ---------- causes v3: MFMA, weights resident in registers as bf16 A-fragments ----------
__global__ void __launch_bounds__(512,2) causes3_kernel(
    const float* __restrict__ net_wih, const float* __restrict__ net_whh,
    const float* __restrict__ net_bih, const float* __restrict__ net_bhh,
    const float* __restrict__ ws, float* __restrict__ out){
  __shared__ __align__(16) u16 bF[14*16*32];   // [chunk][n=16][k=32] bf16 B-staging
  __shared__ float g_rz[320*10];
  __shared__ float g_nh[160*10];
  __shared__ float g_np[160*10];
  int kk = blockIdx.x & 63, bg = blockIdx.x >> 6, b0 = bg*8;
  int tid = threadIdx.x;
  int w = tid >> 6, lane = tid & 63, quad = lane >> 4, n16 = lane & 15;
  const float* whhk = net_whh + (size_t)kk*H3c*Hc;
  const float* wihk = net_wih + (size_t)kk*H3c*Wc;
  const float* bihk = net_bih + kk*H3c;
  const float* bhhk = net_bhh + kk*H3c;

  short8 whhA[4][5], wihA[4][4];
  #pragma unroll
  for (int ti=0; ti<4; ti++){
    int tile = w*4 + ti;
    int sec = tile/10;
    int sr = (tile - sec*10)*16 + n16;
    bool rowok = (tile < 30) && (sr < Hc);
    int grow = sec*Hc + sr;
    #pragma unroll
    for (int c=0;c<5;c++){
      union { short8 v; u16 u[8]; } t8;
      #pragma unroll
      for (int j=0;j<8;j++){
        int k = c*32 + quad*8 + j;
        float v = (rowok && k < Hc) ? whhk[(size_t)grow*Hc + k] : 0.f;
        t8.u[j] = f2us(v);
      }
      whhA[ti][c] = t8.v;
    }
    #pragma unroll
    for (int c=0;c<4;c++){
      union { short8 v; u16 u[8]; } t8;
      #pragma unroll
      for (int j=0;j<8;j++){
        int k = c*32 + quad*8 + j;
        float v = (rowok && k < Wc) ? wihk[(size_t)grow*Wc + k] : 0.f;
        t8.u[j] = f2us(v);
      }
      wihA[ti][c] = t8.v;
    }
  }

  for (int i=tid; i<14*16*32/2; i+=512) ((u32*)bF)[i] = 0u;
  __syncthreads();

  float hst[3] = {0.f,0.f,0.f};
  float brz_r[3], brz_z[3], bnh_[3], bnp_[3];
  #pragma unroll
  for (int q=0;q<3;q++){
    int task = tid + q*512;
    if (task < 1200){
      int t = task >> 3, bb = task & 7;
      float h = ws[OFF_Z + (b0+bb)*Hc + t];
      hst[q] = h;
      brz_r[q] = bhhk[t]      + bihk[t];
      brz_z[q] = bhhk[Hc+t]   + bihk[Hc+t];
      bnh_[q]  = bhhk[2*Hc+t];
      bnp_[q]  = bihk[2*Hc+t];
      u16 hi = f2us(h); float hif = us2f(hi); u16 lo = f2us(h - hif);
      bF[((t>>5)*16 + bb)*32 + (t&31)] = hi;
      bF[((5 + (t>>5))*16 + bb)*32 + (t&31)] = lo;
    }
  }
  for (int it=tid; it<800; it+=512){
    int bb = it/100, i = it - bb*100;
    float xv = ws[OFF_WX + (b0+bb)*KWc + i];
    bF[((10 + (i>>5))*16 + bb)*32 + (i&31)] = f2us(xv);
  }

  const bool isN = (w >= 5);
  for (int s=0;s<Kc;s++){
    __syncthreads();
    floatx4 accH[4] = {{0.f,0.f,0.f,0.f},{0.f,0.f,0.f,0.f},{0.f,0.f,0.f,0.f},{0.f,0.f,0.f,0.f}};
    floatx4 accP[4] = {{0.f,0.f,0.f,0.f},{0.f,0.f,0.f,0.f},{0.f,0.f,0.f,0.f},{0.f,0.f,0.f,0.f}};
    const u16* bBase = bF + (size_t)n16*32 + (size_t)quad*8;
    short8 bcur = *(const short8*)bBase;
    #pragma unroll
    for (int c=0;c<14;c++){
      short8 bnext = bcur;
      if (c<13) bnext = *(const short8*)(bBase + (size_t)(c+1)*512);
      short8 b = bcur;
      if (c < 10){
        int ca = (c<5)? c : (c-5);
        #pragma unroll
        for (int ti=0;ti<4;ti++)
          accH[ti] = __builtin_amdgcn_mfma_f32_16x16x32_bf16(whhA[ti][ca], b, accH[ti], 0,0,0);
      } else {
        int ca = c-10;
        if (isN){
          #pragma unroll
          for (int ti=0;ti<4;ti++)
            accP[ti] = __builtin_amdgcn_mfma_f32_16x16x32_bf16(wihA[ti][ca], b, accP[ti], 0,0,0);
        } else {
          #pragma unroll
          for (int ti=0;ti<4;ti++)
            accH[ti] = __builtin_amdgcn_mfma_f32_16x16x32_bf16(wihA[ti][ca], b, accH[ti], 0,0,0);
        }
      }
      bcur = bnext;
    }
    if (n16 < 8){
      #pragma unroll
      for (int ti=0;ti<4;ti++){
        int tile = w*4 + ti;
        if (tile < 30){
          int sec = tile/10;
          int srb = (tile - sec*10)*16 + quad*4;
          if (sec < 2){
            float* gp = g_rz + (sec*160 + srb)*10 + n16;
            #pragma unroll
            for (int r=0;r<4;r++) gp[r*10] = accH[ti][r];
          } else {
            float* gh = g_nh + srb*10 + n16;
            float* gq = g_np + srb*10 + n16;
            #pragma unroll
            for (int r=0;r<4;r++){ gh[r*10] = accH[ti][r]; gq[r*10] = accP[ti][r]; }
          }
        }
      }
    }
    __syncthreads();
    #pragma unroll
    for (int q=0;q<3;q++){
      int task = tid + q*512;
      if (task < 1200){
        int t = task >> 3, bb = task & 7;
        float a_r = g_rz[t*10+bb] + brz_r[q];
        float a_z = g_rz[(160+t)*10+bb] + brz_z[q];
        float r  = 1.f/(1.f+__expf(-a_r));
        float zz = 1.f/(1.f+__expf(-a_z));
        float nx = (g_np[t*10+bb] + bnp_[q]) + r*(g_nh[t*10+bb] + bnh_[q]);
        nx = fminf(fmaxf(nx,-15.f),15.f);
        float e2 = __expf(2.f*nx);
        float n = (e2-1.f)/(e2+1.f);
        float h = (1.f-zz)*n + zz*hst[q];
        hst[q] = h;
        u16 hi = f2us(h); float hif = us2f(hi); u16 lo = f2us(h - hif);
        bF[((t>>5)*16 + bb)*32 + (t&31)] = hi;
        bF[((5 + (t>>5))*16 + bb)*32 + (t&31)] = lo;
      }
    }
    if (s < Kc-1){
      for (int it=tid; it<800; it+=512){
        int bb = it/100, i = it - bb*100;
        float xv = ws[OFF_WX + (b0+bb)*KWc + (s+1)*Wc + i];
        bF[((10 + (i>>5))*16 + bb)*32 + (i&31)] = f2us(xv);
      }
    }
  }
  #pragma unroll
  for (int q=0;q<3;q++){
    int task = tid + q*512;
    if (task < 1200){
      int t = task >> 3, bb = task & 7;
      out[((size_t)(b0+bb)*Kc + kk)*Hc + t] = hst[q];
    }
  }
}

extern "C" void kernel_launch(void* const* d_in, const int* in_sizes, int n_in,
                              void* d_out, int out_size, void* d_ws, size_t ws_size,
                              hipStream_t stream){
  const float* x        = (const float*)d_in[0];
  const float* y        = (const float*)d_in[1];
  const float* z_noise  = (const float*)d_in[2];
  const float* lin_w    = (const float*)d_in[3];
  const float* lin_b    = (const float*)d_in[4];
  const float* a        = (const float*)d_in[5];
  const float* bias     = (const float*)d_in[6];
  const float* gl_wih   = (const float*)d_in[7];
  const float* gl_whh   = (const float*)d_in[8];
  const float* gl_bih   = (const float*)d_in[9];
  const float* gl_bhh   = (const float*)d_in[10];
  const float* mu_w     = (const float*)d_in[11];
  const float* mu_b     = (const float*)d_in[12];
  const float* std_w    = (const float*)d_in[13];
  const float* std_b    = (const float*)d_in[14];
  const float* net_wih  = (const float*)d_in[15];
  const float* net_whh  = (const float*)d_in[16];
  const float* net_bih  = (const float*)d_in[17];
  const float* net_bhh  = (const float*)d_in[18];
  float* ws = (float*)d_ws;
  float* out = (float*)d_out;

  wx_kernel<<<(Bc*KWc+255)/256, 256, 0, stream>>>(x, lin_w, lin_b, ws);
  attn_kernel<<<Bc*Kc, 256, 0, stream>>>(y, a, bias, ws);
  glproj_kernel<<<(Kc*Bc*H3c+255)/256, 256, 0, stream>>>(gl_wih, gl_bih, ws);
  glgru4_kernel<<<2, 512, 0, stream>>>(gl_whh, gl_bhh, ws);
  z_kernel<<<(Bc*Hc+255)/256, 256, 0, stream>>>(z_noise, mu_w, mu_b, std_w, std_b, ws);
  causes3_kernel<<<Kc*4, 512, 0, stream>>>(net_wih, net_whh, net_bih, net_bhh, ws, out);
}

// Round 8
// 539.453 us; speedup vs baseline: 24.8645x; 1.0936x over previous
//
#include <hip/hip_runtime.h>

#define Bc 32
#define Kc 64
#define Wc 100
#define Hc 150
#define H3c 450
#define KWc 6400
#define ALPHAc 0.2f
#define THRESc 0.0002f

typedef unsigned int u32;
typedef unsigned short u16;
typedef __attribute__((ext_vector_type(8))) short short8;   // 8 bf16
typedef __attribute__((ext_vector_type(4))) float floatx4;  // 4 f32 acc

// ---- ws layout (float offsets), 4.55 MB ----
#define OFF_WX      0u          // 204800  Wx (B,K,W) fp32
#define OFF_CS      204800u     // 2048    causesum (B,K)
#define OFF_GX      206848u     // 921600  gl proj (s,b,g)
#define OFF_HT      1128448u    // 4800    h_t (B,H)
#define OFF_Z       1133248u    // 4800    z (B,H)

__device__ __forceinline__ float us2f(u16 u){ u32 x=((u32)u)<<16; return __uint_as_float(x); }
__device__ __forceinline__ u16 f2us(float f){
  u32 x = __float_as_uint(f);
  u32 r = (x + 0x7fffu + ((x>>16)&1u)) >> 16;   // RNE bf16
  return (u16)r;
}

// ---------- Wx = x @ lin_w.T + lin_b ----------
__global__ void wx_kernel(const float* __restrict__ x, const float* __restrict__ lin_w,
                          const float* __restrict__ lin_b, float* __restrict__ ws){
  int o = blockIdx.x*256 + threadIdx.x;
  if (o >= Bc*KWc) return;
  int i = o % Wc;
  int bk = o / Wc;
  const float4* xr = (const float4*)(x + bk*Wc);
  const float4* wr = (const float4*)(lin_w + i*Wc);
  float acc = lin_b[i];
  #pragma unroll
  for (int j=0;j<25;j++){
    float4 xv = xr[j], wv = wr[j];
    acc += xv.x*wv.x + xv.y*wv.y + xv.z*wv.z + xv.w*wv.w;
  }
  ws[OFF_WX + o] = acc;
}

// ---------- attention softmax + thresholded sum ----------
__global__ void attn_kernel(const float* __restrict__ y, const float* __restrict__ a,
                            const float* __restrict__ bias, float* __restrict__ ws){
  __shared__ float e_l[KWc];
  __shared__ float red[4];
  int row = blockIdx.x;          // b*64 + k
  int b = row >> 6, k = row & 63;
  int tid = threadIdx.x;
  float a0 = a[0], a1 = a[1];
  float yv = y[row];
  const float* v = ws + OFF_WX + b*KWc;
  const float* br = bias + k*KWc;
  float m = -3.4e38f;
  for (int j=tid; j<KWc; j+=256){
    float e = a0*yv + a1*v[j] + br[j];
    e = (e >= 0.f) ? e : ALPHAc*e;
    e_l[j] = e;
    m = fmaxf(m, e);
  }
  for (int o=32;o;o>>=1) m = fmaxf(m, __shfl_down(m, o));
  if ((tid&63)==0) red[tid>>6] = m;
  __syncthreads();
  m = fmaxf(fmaxf(red[0],red[1]), fmaxf(red[2],red[3]));
  __syncthreads();
  float ssum = 0.f;
  for (int j=tid; j<KWc; j+=256){
    float ex = expf(e_l[j]-m);
    e_l[j] = ex;
    ssum += ex;
  }
  for (int o=32;o;o>>=1) ssum += __shfl_down(ssum, o);
  if ((tid&63)==0) red[tid>>6] = ssum;
  __syncthreads();
  float s = red[0]+red[1]+red[2]+red[3];
  __syncthreads();
  float cs = 0.f;
  for (int j=tid; j<KWc; j+=256){
    float att = e_l[j] / s;
    if (att >= THRESc) cs += v[j];
  }
  for (int o=32;o;o>>=1) cs += __shfl_down(cs, o);
  if ((tid&63)==0) red[tid>>6] = cs;
  __syncthreads();
  if (tid==0) ws[OFF_CS + row] = red[0]+red[1]+red[2]+red[3];
}

// ---------- gl input projection ----------
__global__ void glproj_kernel(const float* __restrict__ gl_wih, const float* __restrict__ gl_bih,
                              float* __restrict__ ws){
  int o = blockIdx.x*256 + threadIdx.x;
  if (o >= Kc*Bc*H3c) return;
  int g = o % H3c;
  int t = o / H3c;               // s*32 + b
  int b = t & 31, s = t >> 5;
  float cs = ws[OFF_CS + b*Kc + s];
  const float4* xr = (const float4*)(ws + OFF_WX + b*KWc + s*Wc);
  const float4* wr = (const float4*)(gl_wih + g*Wc);
  float acc = gl_bih[g];
  #pragma unroll
  for (int j=0;j<25;j++){
    float4 wv = wr[j], xv = xr[j];
    acc += (xv.x+cs)*wv.x + (xv.y+cs)*wv.y + (xv.z+cs)*wv.z + (xv.w+cs)*wv.w;
  }
  ws[OFF_GX + o] = acc;
}

// ---------- gl recurrent GRU v5: MFMA, 4 blocks x 8 batches, conflict-free LDS ----------
// bF row stride 40 u16 -> B-read + h-writes hit all 32 banks evenly.
__global__ void __launch_bounds__(512,1) glgru4_kernel(
    const float* __restrict__ gl_whh, const float* __restrict__ gl_bhh,
    float* __restrict__ ws){
  __shared__ __align__(16) u16 bF[10*16*40];   // [chunk][n=16(8 used)][k-row stride 40]
  __shared__ float g_l[480*10];                // gate rows x 8 batches, stride 10
  int b0 = blockIdx.x*8;
  int tid = threadIdx.x;
  int w = tid >> 6, lane = tid & 63, quad = lane >> 4, n16 = lane & 15;

  // ---- resident A-fragments: A[m=lane&15][k=quad*8+j], bf16 ----
  short8 whhA[4][5];
  #pragma unroll
  for (int ti=0; ti<4; ti++){
    int tile = w*4 + ti;                 // 0..31 (30,31 dummy)
    int sec = tile/10;                   // 0=r,1=z,2=n
    int sr = (tile - sec*10)*16 + n16;   // row within 160-padded section
    bool rowok = (tile < 30) && (sr < Hc);
    int grow = sec*Hc + sr;
    #pragma unroll
    for (int c=0;c<5;c++){
      union { short8 v; u16 u[8]; } t8;
      #pragma unroll
      for (int j=0;j<8;j++){
        int k = c*32 + quad*8 + j;
        float v = (rowok && k < Hc) ? gl_whh[(size_t)grow*Hc + k] : 0.f;
        t8.u[j] = f2us(v);
      }
      whhA[ti][c] = t8.v;
    }
  }
  // zero B staging (pads stay zero; h0 = 0)
  for (int i=tid; i<10*16*40/2; i+=512) ((u32*)bF)[i] = 0u;

  // ---- per-task state: 1200 tasks, <=3/thread, bl = tau/150, t = tau%150 ----
  float hst[3] = {0.f,0.f,0.f};
  float bh_r[3], bh_z[3], bh_n[3];
  int tT[3], tBL[3];
  #pragma unroll
  for (int q=0;q<3;q++){
    int task = tid + q*512;
    if (task < 1200){
      int bl = task/150, t = task - bl*150;
      tT[q] = t; tBL[q] = bl;
      bh_r[q] = gl_bhh[t];
      bh_z[q] = gl_bhh[Hc+t];
      bh_n[q] = gl_bhh[2*Hc+t];
    } else { tT[q] = 0; tBL[q] = -1; }
  }

  for (int s=0;s<Kc;s++){
    __syncthreads();   // bF ready
    // prefetch gx, coalesced in t (overlaps MFMA)
    float gxr[3], gxz[3], gxn[3];
    const float* gxb = ws + OFF_GX + (size_t)(s*Bc)*H3c;
    #pragma unroll
    for (int q=0;q<3;q++){
      if (tBL[q] >= 0){
        const float* gp = gxb + (size_t)(b0+tBL[q])*H3c;
        int t = tT[q];
        gxr[q] = gp[t]; gxz[q] = gp[Hc+t]; gxn[q] = gp[2*Hc+t];
      }
    }
    // MFMA stage
    floatx4 acc[4] = {{0.f,0.f,0.f,0.f},{0.f,0.f,0.f,0.f},{0.f,0.f,0.f,0.f},{0.f,0.f,0.f,0.f}};
    const u16* bBase = bF + (size_t)n16*40 + (size_t)quad*8;
    #pragma unroll
    for (int c=0;c<10;c++){
      short8 b8 = *(const short8*)(bBase + (size_t)c*640);
      int ca = (c<5)? c : (c-5);
      #pragma unroll
      for (int ti=0;ti<4;ti++)
        acc[ti] = __builtin_amdgcn_mfma_f32_16x16x32_bf16(whhA[ti][ca], b8, acc[ti], 0,0,0);
    }
    // C -> LDS (C layout: col=lane&15, row=quad*4+reg); only 8 batches used
    if (n16 < 8){
      #pragma unroll
      for (int ti=0;ti<4;ti++){
        int tile = w*4 + ti;
        if (tile < 30){
          int row0 = tile*16 + quad*4;
          float* gp = g_l + row0*10 + n16;
          #pragma unroll
          for (int r=0;r<4;r++) gp[r*10] = acc[ti][r];
        }
      }
    }
    __syncthreads();   // gates ready; bF MFMA reads done
    #pragma unroll
    for (int q=0;q<3;q++){
      if (tBL[q] >= 0){
        int t = tT[q], bl = tBL[q];
        float a_r = gxr[q] + g_l[t*10+bl] + bh_r[q];
        float a_z = gxz[q] + g_l[(160+t)*10+bl] + bh_z[q];
        float r  = 1.f/(1.f+__expf(-a_r));
        float zz = 1.f/(1.f+__expf(-a_z));
        float nx = gxn[q] + r*(g_l[(320+t)*10+bl] + bh_n[q]);
        nx = fminf(fmaxf(nx,-15.f),15.f);
        float e2 = __expf(2.f*nx);
        float n = (e2-1.f)/(e2+1.f);
        float h = (1.f-zz)*n + zz*hst[q];
        hst[q] = h;
        u16 hi = f2us(h); float hif = us2f(hi); u16 lo = f2us(h - hif);
        bF[(t>>5)*640 + bl*40 + (t&31)] = hi;
        bF[(5+(t>>5))*640 + bl*40 + (t&31)] = lo;
      }
    }
  }
  #pragma unroll
  for (int q=0;q<3;q++){
    if (tBL[q] >= 0)
      ws[OFF_HT + (size_t)(b0+tBL[q])*Hc + tT[q]] = hst[q];
  }
}

// ---------- z = mu + sigma * z_noise ----------
__global__ void z_kernel(const float* __restrict__ z_noise, const float* __restrict__ mu_w,
                         const float* __restrict__ mu_b, const float* __restrict__ std_w,
                         const float* __restrict__ std_b, float* __restrict__ ws){
  int o = blockIdx.x*256 + threadIdx.x;
  if (o >= Bc*Hc) return;
  int t = o % Hc, b = o / Hc;
  const float* h = ws + OFF_HT + b*Hc;
  const float2* mwr = (const float2*)(mu_w + t*Hc);
  const float2* swr = (const float2*)(std_w + t*Hc);
  float mu = mu_b[t], lv = std_b[t];
  for (int j=0;j<Hc/2;j++){
    float2 mw = mwr[j], sw = swr[j];
    float h0 = h[2*j], h1 = h[2*j+1];
    mu += h0*mw.x + h1*mw.y;
    lv += h0*sw.x + h1*sw.y;
  }
  float sg = expf(0.5f*lv);
  ws[OFF_Z + o] = mu + sg*z_noise[o];
}

// ---------- causes v3: MFMA, reg-resident weights, conflict-free bF (stride 40) ----------
__global__ void __launch_bounds__(512,2) causes3_kernel(
    const float* __restrict__ net_wih, const float* __restrict__ net_whh,
    const float* __restrict__ net_bih, const float* __restrict__ net_bhh,
    const float* __restrict__ ws, float* __restrict__ out){
  __shared__ __align__(16) u16 bF[14*16*40];   // [chunk][n=16(8 used)][k-row stride 40]
  __shared__ float g_rz[320*10];
  __shared__ float g_nh[160*10];
  __shared__ float g_np[160*10];
  int kk = blockIdx.x & 63, bg = blockIdx.x >> 6, b0 = bg*8;
  int tid = threadIdx.x;
  int w = tid >> 6, lane = tid & 63, quad = lane >> 4, n16 = lane & 15;
  const float* whhk = net_whh + (size_t)kk*H3c*Hc;
  const float* wihk = net_wih + (size_t)kk*H3c*Wc;
  const float* bihk = net_bih + kk*H3c;
  const float* bhhk = net_bhh + kk*H3c;

  short8 whhA[4][5], wihA[4][4];
  #pragma unroll
  for (int ti=0; ti<4; ti++){
    int tile = w*4 + ti;
    int sec = tile/10;
    int sr = (tile - sec*10)*16 + n16;
    bool rowok = (tile < 30) && (sr < Hc);
    int grow = sec*Hc + sr;
    #pragma unroll
    for (int c=0;c<5;c++){
      union { short8 v; u16 u[8]; } t8;
      #pragma unroll
      for (int j=0;j<8;j++){
        int k = c*32 + quad*8 + j;
        float v = (rowok && k < Hc) ? whhk[(size_t)grow*Hc + k] : 0.f;
        t8.u[j] = f2us(v);
      }
      whhA[ti][c] = t8.v;
    }
    #pragma unroll
    for (int c=0;c<4;c++){
      union { short8 v; u16 u[8]; } t8;
      #pragma unroll
      for (int j=0;j<8;j++){
        int k = c*32 + quad*8 + j;
        float v = (rowok && k < Wc) ? wihk[(size_t)grow*Wc + k] : 0.f;
        t8.u[j] = f2us(v);
      }
      wihA[ti][c] = t8.v;
    }
  }

  for (int i=tid; i<14*16*40/2; i+=512) ((u32*)bF)[i] = 0u;
  __syncthreads();

  float hst[3] = {0.f,0.f,0.f};
  float brz_r[3], brz_z[3], bnh_[3], bnp_[3];
  #pragma unroll
  for (int q=0;q<3;q++){
    int task = tid + q*512;
    if (task < 1200){
      int t = task >> 3, bb = task & 7;
      float h = ws[OFF_Z + (b0+bb)*Hc + t];
      hst[q] = h;
      brz_r[q] = bhhk[t]      + bihk[t];
      brz_z[q] = bhhk[Hc+t]   + bihk[Hc+t];
      bnh_[q]  = bhhk[2*Hc+t];
      bnp_[q]  = bihk[2*Hc+t];
      u16 hi = f2us(h); float hif = us2f(hi); u16 lo = f2us(h - hif);
      bF[(t>>5)*640 + bb*40 + (t&31)] = hi;
      bF[(5+(t>>5))*640 + bb*40 + (t&31)] = lo;
    }
  }
  for (int it=tid; it<800; it+=512){
    int bb = it/100, i = it - bb*100;
    float xv = ws[OFF_WX + (b0+bb)*KWc + i];
    bF[(10+(i>>5))*640 + bb*40 + (i&31)] = f2us(xv);
  }

  const bool isN = (w >= 5);
  for (int s=0;s<Kc;s++){
    __syncthreads();
    floatx4 accH[4] = {{0.f,0.f,0.f,0.f},{0.f,0.f,0.f,0.f},{0.f,0.f,0.f,0.f},{0.f,0.f,0.f,0.f}};
    floatx4 accP[4] = {{0.f,0.f,0.f,0.f},{0.f,0.f,0.f,0.f},{0.f,0.f,0.f,0.f},{0.f,0.f,0.f,0.f}};
    const u16* bBase = bF + (size_t)n16*40 + (size_t)quad*8;
    short8 bcur = *(const short8*)bBase;
    #pragma unroll
    for (int c=0;c<14;c++){
      short8 bnext = bcur;
      if (c<13) bnext = *(const short8*)(bBase + (size_t)(c+1)*640);
      short8 b = bcur;
      if (c < 10){
        int ca = (c<5)? c : (c-5);
        #pragma unroll
        for (int ti=0;ti<4;ti++)
          accH[ti] = __builtin_amdgcn_mfma_f32_16x16x32_bf16(whhA[ti][ca], b, accH[ti], 0,0,0);
      } else {
        int ca = c-10;
        if (isN){
          #pragma unroll
          for (int ti=0;ti<4;ti++)
            accP[ti] = __builtin_amdgcn_mfma_f32_16x16x32_bf16(wihA[ti][ca], b, accP[ti], 0,0,0);
        } else {
          #pragma unroll
          for (int ti=0;ti<4;ti++)
            accH[ti] = __builtin_amdgcn_mfma_f32_16x16x32_bf16(wihA[ti][ca], b, accH[ti], 0,0,0);
        }
      }
      bcur = bnext;
    }
    if (n16 < 8){
      #pragma unroll
      for (int ti=0;ti<4;ti++){
        int tile = w*4 + ti;
        if (tile < 30){
          int sec = tile/10;
          int srb = (tile - sec*10)*16 + quad*4;
          if (sec < 2){
            float* gp = g_rz + (sec*160 + srb)*10 + n16;
            #pragma unroll
            for (int r=0;r<4;r++) gp[r*10] = accH[ti][r];
          } else {
            float* gh = g_nh + srb*10 + n16;
            float* gq = g_np + srb*10 + n16;
            #pragma unroll
            for (int r=0;r<4;r++){ gh[r*10] = accH[ti][r]; gq[r*10] = accP[ti][r]; }
          }
        }
      }
    }
    __syncthreads();
    #pragma unroll
    for (int q=0;q<3;q++){
      int task = tid + q*512;
      if (task < 1200){
        int t = task >> 3, bb = task & 7;
        float a_r = g_rz[t*10+bb] + brz_r[q];
        float a_z = g_rz[(160+t)*10+bb] + brz_z[q];
        float r  = 1.f/(1.f+__expf(-a_r));
        float zz = 1.f/(1.f+__expf(-a_z));
        float nx = (g_np[t*10+bb] + bnp_[q]) + r*(g_nh[t*10+bb] + bnh_[q]);
        nx = fminf(fmaxf(nx,-15.f),15.f);
        float e2 = __expf(2.f*nx);
        float n = (e2-1.f)/(e2+1.f);
        float h = (1.f-zz)*n + zz*hst[q];
        hst[q] = h;
        u16 hi = f2us(h); float hif = us2f(hi); u16 lo = f2us(h - hif);
        bF[(t>>5)*640 + bb*40 + (t&31)] = hi;
        bF[(5+(t>>5))*640 + bb*40 + (t&31)] = lo;
      }
    }
    if (s < Kc-1){
      for (int it=tid; it<800; it+=512){
        int bb = it/100, i = it - bb*100;
        float xv = ws[OFF_WX + (b0+bb)*KWc + (s+1)*Wc + i];
        bF[(10+(i>>5))*640 + bb*40 + (i&31)] = f2us(xv);
      }
    }
  }
  #pragma unroll
  for (int q=0;q<3;q++){
    int task = tid + q*512;
    if (task < 1200){
      int t = task >> 3, bb = task & 7;
      out[((size_t)(b0+bb)*Kc + kk)*Hc + t] = hst[q];
    }
  }
}

extern "C" void kernel_launch(void* const* d_in, const int* in_sizes, int n_in,
                              void* d_out, int out_size, void* d_ws, size_t ws_size,
                              hipStream_t stream){
  const float* x        = (const float*)d_in[0];
  const float* y        = (const float*)d_in[1];
  const float* z_noise  = (const float*)d_in[2];
  const float* lin_w    = (const float*)d_in[3];
  const float* lin_b    = (const float*)d_in[4];
  const float* a        = (const float*)d_in[5];
  const float* bias     = (const float*)d_in[6];
  const float* gl_wih   = (const float*)d_in[7];
  const float* gl_whh   = (const float*)d_in[8];
  const float* gl_bih   = (const float*)d_in[9];
  const float* gl_bhh   = (const float*)d_in[10];
  const float* mu_w     = (const float*)d_in[11];
  const float* mu_b     = (const float*)d_in[12];
  const float* std_w    = (const float*)d_in[13];
  const float* std_b    = (const float*)d_in[14];
  const float* net_wih  = (const float*)d_in[15];
  const float* net_whh  = (const float*)d_in[16];
  const float* net_bih  = (const float*)d_in[17];
  const float* net_bhh  = (const float*)d_in[18];
  float* ws = (float*)d_ws;
  float* out = (float*)d_out;

  wx_kernel<<<(Bc*KWc+255)/256, 256, 0, stream>>>(x, lin_w, lin_b, ws);
  attn_kernel<<<Bc*Kc, 256, 0, stream>>>(y, a, bias, ws);
  glproj_kernel<<<(Kc*Bc*H3c+255)/256, 256, 0, stream>>>(gl_wih, gl_bih, ws);
  glgru4_kernel<<<4, 512, 0, stream>>>(gl_whh, gl_bhh, ws);
  z_kernel<<<(Bc*Hc+255)/256, 256, 0, stream>>>(z_noise, mu_w, mu_b, std_w, std_b, ws);
  causes3_kernel<<<Kc*4, 512, 0, stream>>>(net_wih, net_whh, net_bih, net_bhh, ws, out);
}